// Round 2
// baseline (4530.013 us; speedup 1.0000x reference)
//
#include <hip/hip_runtime.h>
#include <hip/hip_bf16.h>
#include <math.h>

// Problem constants
#define BATCH 32     // per-pass batch (H pass then F pass)
#define SEQ  512
#define DIM  512
#define MM   1000
#define NHEAD 8
#define DHEAD 64
#define DFFN 2048
#define ROWS (BATCH * SEQ)   // 16384 rows per pass

// ---------------------------------------------------------------------------
// ws layout (float offsets) — total 34,603,008 floats = 138.4 MB
//   WmT    @ 0         : 1000*512 = 512000
//   mask   @ 524288    : 16384
//   pooled @ 540672    : 16384
//   henc   @ 557056    : 64*512 = 32768   (rows 0..31 = H, 32..63 = F)
//   logits @ 589824    : 32*1000 = 32000
//   e      @ 1048576   : 16384*512 = 8388608   (becomes h in-place)
//   QO     @ 9437184   : 8388608   (Q, overwritten in-place by attention O)
//   K      @ 17825792  : 8388608   (K+V span reused as FFN intermediate r)
//   V      @ 26214400  : 8388608
// ---------------------------------------------------------------------------

// ---------------- transpose W_m [512,1000] -> WmT [1000,512] ----------------
__global__ __launch_bounds__(256)
void transpose_wm(const float* __restrict__ Wm, float* __restrict__ WmT)
{
    __shared__ float tile[32][33];
    int tx = threadIdx.x & 31;
    int ty = threadIdx.x >> 5;            // 0..7
    int mx = blockIdx.x * 32;             // marker dim
    int dy = blockIdx.y * 32;             // feature dim
    for (int i = ty; i < 32; i += 8) {
        int d = dy + i, m = mx + tx;
        tile[i][tx] = (m < MM) ? Wm[(size_t)d * MM + m] : 0.f;
    }
    __syncthreads();
    for (int i = ty; i < 32; i += 8) {
        int m = mx + i, d = dy + tx;
        if (m < MM) WmT[(size_t)m * DIM + d] = tile[tx][i];
    }
}

// ---------------- embedding + mask (one pass: 32 sequences) ----------------
__global__ __launch_bounds__(256)
void embed_kernel(const float* __restrict__ x,
                  const float* __restrict__ WmT, const float* __restrict__ Wt,
                  const float* __restrict__ bt,
                  float* __restrict__ e, float* __restrict__ maskA)
{
    int bs = blockIdx.x;                  // b*SEQ + s, 0..16383
    const float* xp = x + (size_t)bs * 2;
    float t   = xp[0];
    float mkf = xp[1];
    int   mk  = (int)fminf(fmaxf(mkf, 0.f), (float)(MM - 1));
    bool  valid = (t >= 0.f);
    if (threadIdx.x == 0) maskA[bs] = valid ? 1.f : 0.f;
    const float* wrow = WmT + (size_t)mk * DIM;
    size_t base = (size_t)bs * DIM;
    for (int d = threadIdx.x; d < DIM; d += 256) {
        float v = 0.5f * wrow[d] + 0.5f * (Wt[d] * t + bt[d]);
        e[base + d] = valid ? v : 0.f;
    }
}

// ---------------- fp32 SGEMM: C = [R +] A@B [+ bias] [relu] ----------------
// A [Md,Kd] row-major, B [Kd,Nd] row-major, C [Md,Nd].
// BM=BN=128, BK=16, 256 threads, 8x8 micro-tile.
template<bool BIAS, bool RELU, bool RES>
__global__ __launch_bounds__(256)
void sgemm(const float* __restrict__ A, const float* __restrict__ B,
           const float* __restrict__ bias, const float* __restrict__ R,
           float* __restrict__ C, int Md, int Nd, int Kd)
{
    __shared__ float As[16][132];
    __shared__ float Bs[16][132];
    const int tid  = threadIdx.x;
    const int row0 = blockIdx.y * 128;
    const int col0 = blockIdx.x * 128;
    const int ty = tid >> 4;              // 0..15
    const int tx = tid & 15;              // 0..15
    const int ar = tid >> 2;              // 0..63
    const int ac = (tid & 3) << 2;        // 0,4,8,12
    const int br = tid >> 5;              // 0..7
    const int bc = (tid & 31) << 2;       // 0..124

    float acc[8][8];
    #pragma unroll
    for (int i = 0; i < 8; i++)
        #pragma unroll
        for (int j = 0; j < 8; j++) acc[i][j] = 0.f;

    for (int kt = 0; kt < Kd; kt += 16) {
        float4 a0 = *reinterpret_cast<const float4*>(A + (size_t)(row0 + ar)      * Kd + kt + ac);
        float4 a1 = *reinterpret_cast<const float4*>(A + (size_t)(row0 + ar + 64) * Kd + kt + ac);
        float4 b0 = *reinterpret_cast<const float4*>(B + (size_t)(kt + br)     * Nd + col0 + bc);
        float4 b1 = *reinterpret_cast<const float4*>(B + (size_t)(kt + br + 8) * Nd + col0 + bc);
        __syncthreads();
        As[ac + 0][ar] = a0.x;  As[ac + 1][ar] = a0.y;
        As[ac + 2][ar] = a0.z;  As[ac + 3][ar] = a0.w;
        As[ac + 0][ar + 64] = a1.x;  As[ac + 1][ar + 64] = a1.y;
        As[ac + 2][ar + 64] = a1.z;  As[ac + 3][ar + 64] = a1.w;
        *reinterpret_cast<float4*>(&Bs[br][bc])     = b0;
        *reinterpret_cast<float4*>(&Bs[br + 8][bc]) = b1;
        __syncthreads();
        #pragma unroll
        for (int k = 0; k < 16; k++) {
            float a[8], bf[8];
            *reinterpret_cast<float4*>(a)      = *reinterpret_cast<const float4*>(&As[k][ty * 8]);
            *reinterpret_cast<float4*>(a + 4)  = *reinterpret_cast<const float4*>(&As[k][ty * 8 + 4]);
            *reinterpret_cast<float4*>(bf)     = *reinterpret_cast<const float4*>(&Bs[k][tx * 4]);
            *reinterpret_cast<float4*>(bf + 4) = *reinterpret_cast<const float4*>(&Bs[k][64 + tx * 4]);
            #pragma unroll
            for (int i = 0; i < 8; i++)
                #pragma unroll
                for (int j = 0; j < 8; j++)
                    acc[i][j] += a[i] * bf[j];
        }
    }

    const int c0 = col0 + tx * 4;
    const int c1 = col0 + 64 + tx * 4;
    float bia0[4], bia1[4];
    if (BIAS) {
        #pragma unroll
        for (int j = 0; j < 4; j++) { bia0[j] = bias[c0 + j]; bia1[j] = bias[c1 + j]; }
    }
    #pragma unroll
    for (int i = 0; i < 8; i++) {
        int row = row0 + ty * 8 + i;
        size_t base = (size_t)row * Nd;
        float v0[4], v1[4];
        #pragma unroll
        for (int j = 0; j < 4; j++) { v0[j] = acc[i][j]; v1[j] = acc[i][j + 4]; }
        if (BIAS) {
            #pragma unroll
            for (int j = 0; j < 4; j++) { v0[j] += bia0[j]; v1[j] += bia1[j]; }
        }
        if (RES) {
            float4 r0 = *reinterpret_cast<const float4*>(R + base + c0);
            float4 r1 = *reinterpret_cast<const float4*>(R + base + c1);
            v0[0] += r0.x; v0[1] += r0.y; v0[2] += r0.z; v0[3] += r0.w;
            v1[0] += r1.x; v1[1] += r1.y; v1[2] += r1.z; v1[3] += r1.w;
        }
        if (RELU) {
            #pragma unroll
            for (int j = 0; j < 4; j++) { v0[j] = fmaxf(v0[j], 0.f); v1[j] = fmaxf(v1[j], 0.f); }
        }
        *reinterpret_cast<float4*>(C + base + c0) = make_float4(v0[0], v0[1], v0[2], v0[3]);
        *reinterpret_cast<float4*>(C + base + c1) = make_float4(v1[0], v1[1], v1[2], v1[3]);
    }
}

// ---------------- fused flash attention (fp32), O in-place over Q ----------
// grid (BATCH, NHEAD, 2); 256 threads; thread owns one q row.
// Safe aliasing: each block reads only its own (row-range x head-slice) of QO
// (into registers, before the first barrier) and writes the same slice at the
// end; no other block touches it.
__global__ __launch_bounds__(256)
void attn_kernel(float* __restrict__ QO, const float* __restrict__ K,
                 const float* __restrict__ V, const float* __restrict__ maskA)
{
    __shared__ float Ks[64][64];
    __shared__ float Vs[64][64];
    __shared__ float ms[64];
    const int b   = blockIdx.x;
    const int h   = blockIdx.y;
    const int qc  = blockIdx.z;
    const int tid = threadIdx.x;
    const int qrow = qc * 256 + tid;

    float* qptr = QO + (size_t)(b * SEQ + qrow) * DIM + h * DHEAD;
    float q[64];
    #pragma unroll
    for (int d0 = 0; d0 < 64; d0 += 4) {
        float4 t4 = *reinterpret_cast<const float4*>(qptr + d0);
        q[d0] = t4.x; q[d0 + 1] = t4.y; q[d0 + 2] = t4.z; q[d0 + 3] = t4.w;
    }
    float o[64];
    #pragma unroll
    for (int d = 0; d < 64; d++) o[d] = 0.f;
    float mrun = -INFINITY, lrun = 0.f;

    for (int kt = 0; kt < SEQ; kt += 64) {
        __syncthreads();
        const float* kbase = K + (size_t)(b * SEQ + kt) * DIM + h * DHEAD;
        const float* vbase = V + (size_t)(b * SEQ + kt) * DIM + h * DHEAD;
        #pragma unroll
        for (int it = 0; it < 4; it++) {
            int f  = tid + it * 256;      // 0..1023
            int rr = f >> 4;              // 0..63
            int cc = (f & 15) << 2;       // 0..60
            *reinterpret_cast<float4*>(&Ks[rr][cc]) =
                *reinterpret_cast<const float4*>(kbase + (size_t)rr * DIM + cc);
            *reinterpret_cast<float4*>(&Vs[rr][cc]) =
                *reinterpret_cast<const float4*>(vbase + (size_t)rr * DIM + cc);
        }
        if (tid < 64) ms[tid] = maskA[b * SEQ + kt + tid];
        __syncthreads();

        for (int k0 = 0; k0 < 64; k0 += 16) {
            float s[16];
            #pragma unroll
            for (int j = 0; j < 16; j++) {
                float s0 = 0.f, s1 = 0.f, s2 = 0.f, s3 = 0.f;
                #pragma unroll
                for (int d = 0; d < 64; d += 4) {
                    s0 += q[d]     * Ks[k0 + j][d];
                    s1 += q[d + 1] * Ks[k0 + j][d + 1];
                    s2 += q[d + 2] * Ks[k0 + j][d + 2];
                    s3 += q[d + 3] * Ks[k0 + j][d + 3];
                }
                float sv = (s0 + s1) + (s2 + s3);
                s[j] = (ms[k0 + j] != 0.f) ? sv * 0.125f : -1e9f;
            }
            float tm = s[0];
            #pragma unroll
            for (int j = 1; j < 16; j++) tm = fmaxf(tm, s[j]);
            float mn = fmaxf(mrun, tm);
            float scale = expf(mrun - mn);
            float ps = 0.f;
            #pragma unroll
            for (int j = 0; j < 16; j++) { s[j] = expf(s[j] - mn); ps += s[j]; }
            lrun = lrun * scale + ps;
            #pragma unroll
            for (int d = 0; d < 64; d++) o[d] *= scale;
            #pragma unroll
            for (int j = 0; j < 16; j++) {
                #pragma unroll
                for (int d = 0; d < 64; d++)
                    o[d] += s[j] * Vs[k0 + j][d];
            }
            mrun = mn;
        }
    }

    float inv = 1.0f / lrun;
    #pragma unroll
    for (int d0 = 0; d0 < 64; d0 += 4) {
        *reinterpret_cast<float4*>(qptr + d0) =
            make_float4(o[d0] * inv, o[d0 + 1] * inv, o[d0 + 2] * inv, o[d0 + 3] * inv);
    }
}

// ---------------- masked mean pool (one pass) ----------------
__global__ __launch_bounds__(512)
void pool_kernel(const float* __restrict__ h, const float* __restrict__ maskA,
                 float* __restrict__ pooled)
{
    int b = blockIdx.x;     // 0..31
    int d = threadIdx.x;    // 512
    float acc = 0.f, cnt = 0.f;
    for (int s = 0; s < SEQ; s++) {
        float mv = maskA[b * SEQ + s];
        acc += mv * h[((size_t)(b * SEQ + s)) * DIM + d];
        cnt += mv;
    }
    pooled[b * DIM + d] = acc / fmaxf(cnt, 1.f);
}

// ---------------- pooled @ Wp + bp -> henc rows [hoff, hoff+32) ------------
__global__ __launch_bounds__(512)
void proj_kernel(const float* __restrict__ pooled, const float* __restrict__ Wp,
                 const float* __restrict__ bp, float* __restrict__ henc, int hoff)
{
    int b = blockIdx.x;     // 0..31
    int j = threadIdx.x;    // 512
    __shared__ float p[DIM];
    p[j] = pooled[b * DIM + j];
    __syncthreads();
    float a0 = 0.f, a1 = 0.f, a2 = 0.f, a3 = 0.f;
    for (int d = 0; d < DIM; d += 4) {
        a0 += p[d]     * Wp[(size_t)d       * DIM + j];
        a1 += p[d + 1] * Wp[(size_t)(d + 1) * DIM + j];
        a2 += p[d + 2] * Wp[(size_t)(d + 2) * DIM + j];
        a3 += p[d + 3] * Wp[(size_t)(d + 3) * DIM + j];
    }
    henc[(size_t)(hoff + b) * DIM + j] = ((a0 + a1) + (a2 + a3)) + bp[j];
}

// ---------------- logits = concat(hH,hF) @ W_out + b_out ----------------
__global__ __launch_bounds__(256)
void logits_kernel(const float* __restrict__ henc, const float* __restrict__ Wout,
                   const float* __restrict__ bout, float* __restrict__ logits)
{
    int b = blockIdx.y;                       // 0..31
    int m = blockIdx.x * 256 + threadIdx.x;   // 0..1023
    __shared__ float hh[2 * DIM];
    for (int j = threadIdx.x; j < DIM; j += 256) {
        hh[j]       = henc[(size_t)b * DIM + j];
        hh[DIM + j] = henc[(size_t)(BATCH + b) * DIM + j];
    }
    __syncthreads();
    if (m < MM) {
        float a0 = 0.f, a1 = 0.f, a2 = 0.f, a3 = 0.f;
        for (int j = 0; j < 2 * DIM; j += 4) {
            a0 += hh[j]     * Wout[(size_t)j       * MM + m];
            a1 += hh[j + 1] * Wout[(size_t)(j + 1) * MM + m];
            a2 += hh[j + 2] * Wout[(size_t)(j + 2) * MM + m];
            a3 += hh[j + 3] * Wout[(size_t)(j + 3) * MM + m];
        }
        logits[b * MM + m] = ((a0 + a1) + (a2 + a3)) + bout[m];
    }
}

// ---------------- softmax + argmax ----------------
__global__ __launch_bounds__(256)
void smax_kernel(const float* __restrict__ logits, float* __restrict__ out)
{
    int b   = blockIdx.x;   // 0..31
    int tid = threadIdx.x;
    __shared__ float red[256];
    __shared__ int   redi[256];

    float v[4];
    float mx = -INFINITY;
    #pragma unroll
    for (int i = 0; i < 4; i++) {
        int m = tid + i * 256;
        if (m < MM) { v[i] = logits[b * MM + m]; mx = fmaxf(mx, v[i]); }
        else v[i] = -INFINITY;
    }
    red[tid] = mx; __syncthreads();
    for (int st = 128; st > 0; st >>= 1) {
        if (tid < st) red[tid] = fmaxf(red[tid], red[tid + st]);
        __syncthreads();
    }
    mx = red[0]; __syncthreads();

    float sum = 0.f;
    #pragma unroll
    for (int i = 0; i < 4; i++) {
        int m = tid + i * 256;
        if (m < MM) { v[i] = expf(v[i] - mx); sum += v[i]; }
    }
    red[tid] = sum; __syncthreads();
    for (int st = 128; st > 0; st >>= 1) {
        if (tid < st) red[tid] += red[tid + st];
        __syncthreads();
    }
    float inv = 1.0f / red[0]; __syncthreads();

    float bestv = -INFINITY; int besti = 0x7fffffff;
    #pragma unroll
    for (int i = 0; i < 4; i++) {
        int m = tid + i * 256;
        if (m < MM) {
            float lam = v[i] * inv;
            out[b * MM + m] = lam;
            if (lam > bestv) { bestv = lam; besti = m; }
        }
    }
    red[tid] = bestv; redi[tid] = besti; __syncthreads();
    for (int st = 128; st > 0; st >>= 1) {
        if (tid < st) {
            float ov = red[tid + st]; int oi = redi[tid + st];
            if (ov > red[tid] || (ov == red[tid] && oi < redi[tid])) {
                red[tid] = ov; redi[tid] = oi;
            }
        }
        __syncthreads();
    }
    if (tid == 0) out[BATCH * MM + b] = (float)redi[0];
}

// ---------------------------------------------------------------------------
extern "C" void kernel_launch(void* const* d_in, const int* in_sizes, int n_in,
                              void* d_out, int out_size, void* d_ws, size_t ws_size,
                              hipStream_t stream)
{
    const float* xH   = (const float*)d_in[0];
    const float* xF   = (const float*)d_in[1];
    const float* Wm   = (const float*)d_in[2];
    const float* Wt   = (const float*)d_in[3];
    const float* bt   = (const float*)d_in[4];
    const float* Wq   = (const float*)d_in[5];
    const float* Wk   = (const float*)d_in[6];
    const float* Wv   = (const float*)d_in[7];
    const float* Wo   = (const float*)d_in[8];
    const float* W1   = (const float*)d_in[9];
    const float* b1   = (const float*)d_in[10];
    const float* W2   = (const float*)d_in[11];
    const float* b2   = (const float*)d_in[12];
    const float* Wp   = (const float*)d_in[13];
    const float* bp   = (const float*)d_in[14];
    const float* Wout = (const float*)d_in[15];
    const float* bout = (const float*)d_in[16];
    float* out = (float*)d_out;

    float* ws     = (float*)d_ws;
    float* WmT    = ws;
    float* maskA  = ws + 524288;
    float* pooled = ws + 540672;
    float* henc   = ws + 557056;
    float* logits = ws + 589824;
    float* e      = ws + 1048576;
    float* QO     = e  + 8388608;
    float* Kb     = QO + 8388608;
    float* Vb     = Kb + 8388608;
    float* r      = Kb;   // FFN intermediate spans K+V (16,777,216 floats)

    // 1. transpose W_m (shared by both passes)
    transpose_wm<<<dim3(32, 16), 256, 0, stream>>>(Wm, WmT);

    for (int p = 0; p < 2; p++) {
        const float* x = (p == 0) ? xH : xF;
        // 2. embedding + mask
        embed_kernel<<<dim3(ROWS), 256, 0, stream>>>(x, WmT, Wt, bt, e, maskA);
        // 3. Q,K,V projections: [16384,512] @ [512,512]
        sgemm<false, false, false><<<dim3(4, 128), 256, 0, stream>>>(e, Wq, nullptr, nullptr, QO, ROWS, DIM, DIM);
        sgemm<false, false, false><<<dim3(4, 128), 256, 0, stream>>>(e, Wk, nullptr, nullptr, Kb, ROWS, DIM, DIM);
        sgemm<false, false, false><<<dim3(4, 128), 256, 0, stream>>>(e, Wv, nullptr, nullptr, Vb, ROWS, DIM, DIM);
        // 4. fused attention, O overwrites Q
        attn_kernel<<<dim3(BATCH, NHEAD, 2), 256, 0, stream>>>(QO, Kb, Vb, maskA);
        // 5. h = e + O @ Wo  (in-place residual into e)
        sgemm<false, false, true><<<dim3(4, 128), 256, 0, stream>>>(QO, Wo, nullptr, e, e, ROWS, DIM, DIM);
        // 6. FFN in 2 row-chunks of 8192 (r reuses K+V span)
        for (int c = 0; c < 2; c++) {
            float* hc = e + (size_t)c * 8192 * DIM;
            sgemm<true, true, false><<<dim3(DFFN / 128, 64), 256, 0, stream>>>(
                hc, W1, b1, nullptr, r, 8192, DFFN, DIM);
            sgemm<true, false, true><<<dim3(DIM / 128, 64), 256, 0, stream>>>(
                r, W2, b2, hc, hc, 8192, DIM, DFFN);
        }
        // 7. masked mean pool
        pool_kernel<<<dim3(BATCH), 512, 0, stream>>>(e, maskA, pooled);
        // 8. pooled @ Wp + bp -> henc rows [32p, 32p+32)
        proj_kernel<<<dim3(BATCH), 512, 0, stream>>>(pooled, Wp, bp, henc, p * BATCH);
    }

    // 9. logits
    logits_kernel<<<dim3(4, BATCH), 256, 0, stream>>>(henc, Wout, bout, logits);
    // 10. softmax + argmax -> d_out
    smax_kernel<<<dim3(BATCH), 256, 0, stream>>>(logits, out);
}

// Round 3
// 3503.136 us; speedup vs baseline: 1.2931x; 1.2931x over previous
//
#include <hip/hip_runtime.h>
#include <hip/hip_bf16.h>
#include <math.h>

// Problem constants
#define BATCH 32     // per-pass batch (H pass then F pass)
#define SEQ  512
#define DIM  512
#define MM   1000
#define NHEAD 8
#define DHEAD 64
#define DFFN 2048
#define ROWS (BATCH * SEQ)   // 16384 rows per pass

// ---------------------------------------------------------------------------
// ws layout (float offsets) — total 34,603,008 floats = 138.4 MB
//   WmT    @ 0         : 1000*512 = 512000
//   mask   @ 524288    : 16384
//   pooled @ 540672    : 16384
//   henc   @ 557056    : 64*512 = 32768   (rows 0..31 = H, 32..63 = F)
//   logits @ 589824    : 32*1000 = 32000
//   e      @ 1048576   : 16384*512 = 8388608   (becomes h in-place)
//   QO     @ 9437184   : 8388608   (Q, overwritten in-place by attention O)
//   K      @ 17825792  : 8388608   (K+V span reused as FFN intermediate r)
//   V      @ 26214400  : 8388608
// ---------------------------------------------------------------------------

// ---------------- transpose W_m [512,1000] -> WmT [1000,512] ----------------
__global__ __launch_bounds__(256)
void transpose_wm(const float* __restrict__ Wm, float* __restrict__ WmT)
{
    __shared__ float tile[32][33];
    int tx = threadIdx.x & 31;
    int ty = threadIdx.x >> 5;            // 0..7
    int mx = blockIdx.x * 32;             // marker dim
    int dy = blockIdx.y * 32;             // feature dim
    for (int i = ty; i < 32; i += 8) {
        int d = dy + i, m = mx + tx;
        tile[i][tx] = (m < MM) ? Wm[(size_t)d * MM + m] : 0.f;
    }
    __syncthreads();
    for (int i = ty; i < 32; i += 8) {
        int m = mx + i, d = dy + tx;
        if (m < MM) WmT[(size_t)m * DIM + d] = tile[tx][i];
    }
}

// ---------------- embedding + mask (one pass: 32 sequences) ----------------
__global__ __launch_bounds__(256)
void embed_kernel(const float* __restrict__ x,
                  const float* __restrict__ WmT, const float* __restrict__ Wt,
                  const float* __restrict__ bt,
                  float* __restrict__ e, float* __restrict__ maskA)
{
    int bs = blockIdx.x;                  // b*SEQ + s, 0..16383
    const float* xp = x + (size_t)bs * 2;
    float t   = xp[0];
    float mkf = xp[1];
    int   mk  = (int)fminf(fmaxf(mkf, 0.f), (float)(MM - 1));
    bool  valid = (t >= 0.f);
    if (threadIdx.x == 0) maskA[bs] = valid ? 1.f : 0.f;
    const float* wrow = WmT + (size_t)mk * DIM;
    size_t base = (size_t)bs * DIM;
    for (int d = threadIdx.x; d < DIM; d += 256) {
        float v = 0.5f * wrow[d] + 0.5f * (Wt[d] * t + bt[d]);
        e[base + d] = valid ? v : 0.f;
    }
}

// ---------------- fp32 SGEMM: C = [R +] A@B [+ bias] [relu] ----------------
// A [Md,Kd] row-major, B [Kd,Nd] row-major, C [Md,Nd].
// BM=BN=128, BK=16, 256 threads, 8x8 micro-tile.
template<bool BIAS, bool RELU, bool RES>
__global__ __launch_bounds__(256)
void sgemm(const float* __restrict__ A, const float* __restrict__ B,
           const float* __restrict__ bias, const float* __restrict__ R,
           float* __restrict__ C, int Md, int Nd, int Kd)
{
    __shared__ float As[16][132];
    __shared__ float Bs[16][132];
    const int tid  = threadIdx.x;
    const int row0 = blockIdx.y * 128;
    const int col0 = blockIdx.x * 128;
    const int ty = tid >> 4;              // 0..15
    const int tx = tid & 15;              // 0..15
    const int ar = tid >> 2;              // 0..63
    const int ac = (tid & 3) << 2;        // 0,4,8,12
    const int br = tid >> 5;              // 0..7
    const int bc = (tid & 31) << 2;       // 0..124

    float acc[8][8];
    #pragma unroll
    for (int i = 0; i < 8; i++)
        #pragma unroll
        for (int j = 0; j < 8; j++) acc[i][j] = 0.f;

    for (int kt = 0; kt < Kd; kt += 16) {
        float4 a0 = *reinterpret_cast<const float4*>(A + (size_t)(row0 + ar)      * Kd + kt + ac);
        float4 a1 = *reinterpret_cast<const float4*>(A + (size_t)(row0 + ar + 64) * Kd + kt + ac);
        float4 b0 = *reinterpret_cast<const float4*>(B + (size_t)(kt + br)     * Nd + col0 + bc);
        float4 b1 = *reinterpret_cast<const float4*>(B + (size_t)(kt + br + 8) * Nd + col0 + bc);
        __syncthreads();
        As[ac + 0][ar] = a0.x;  As[ac + 1][ar] = a0.y;
        As[ac + 2][ar] = a0.z;  As[ac + 3][ar] = a0.w;
        As[ac + 0][ar + 64] = a1.x;  As[ac + 1][ar + 64] = a1.y;
        As[ac + 2][ar + 64] = a1.z;  As[ac + 3][ar + 64] = a1.w;
        *reinterpret_cast<float4*>(&Bs[br][bc])     = b0;
        *reinterpret_cast<float4*>(&Bs[br + 8][bc]) = b1;
        __syncthreads();
        #pragma unroll
        for (int k = 0; k < 16; k++) {
            float a[8], bf[8];
            *reinterpret_cast<float4*>(a)      = *reinterpret_cast<const float4*>(&As[k][ty * 8]);
            *reinterpret_cast<float4*>(a + 4)  = *reinterpret_cast<const float4*>(&As[k][ty * 8 + 4]);
            *reinterpret_cast<float4*>(bf)     = *reinterpret_cast<const float4*>(&Bs[k][tx * 4]);
            *reinterpret_cast<float4*>(bf + 4) = *reinterpret_cast<const float4*>(&Bs[k][64 + tx * 4]);
            #pragma unroll
            for (int i = 0; i < 8; i++)
                #pragma unroll
                for (int j = 0; j < 8; j++)
                    acc[i][j] += a[i] * bf[j];
        }
    }

    const int c0 = col0 + tx * 4;
    const int c1 = col0 + 64 + tx * 4;
    float bia0[4], bia1[4];
    if (BIAS) {
        #pragma unroll
        for (int j = 0; j < 4; j++) { bia0[j] = bias[c0 + j]; bia1[j] = bias[c1 + j]; }
    }
    #pragma unroll
    for (int i = 0; i < 8; i++) {
        int row = row0 + ty * 8 + i;
        size_t base = (size_t)row * Nd;
        float v0[4], v1[4];
        #pragma unroll
        for (int j = 0; j < 4; j++) { v0[j] = acc[i][j]; v1[j] = acc[i][j + 4]; }
        if (BIAS) {
            #pragma unroll
            for (int j = 0; j < 4; j++) { v0[j] += bia0[j]; v1[j] += bia1[j]; }
        }
        if (RES) {
            float4 r0 = *reinterpret_cast<const float4*>(R + base + c0);
            float4 r1 = *reinterpret_cast<const float4*>(R + base + c1);
            v0[0] += r0.x; v0[1] += r0.y; v0[2] += r0.z; v0[3] += r0.w;
            v1[0] += r1.x; v1[1] += r1.y; v1[2] += r1.z; v1[3] += r1.w;
        }
        if (RELU) {
            #pragma unroll
            for (int j = 0; j < 4; j++) { v0[j] = fmaxf(v0[j], 0.f); v1[j] = fmaxf(v1[j], 0.f); }
        }
        *reinterpret_cast<float4*>(C + base + c0) = make_float4(v0[0], v0[1], v0[2], v0[3]);
        *reinterpret_cast<float4*>(C + base + c1) = make_float4(v1[0], v1[1], v1[2], v1[3]);
    }
}

// ---------------- fused flash attention (fp32), O in-place over Q ----------
// grid (BATCH, NHEAD, 8); 256 threads; 4 threads per q-row (16-dim slices),
// butterfly shfl_xor(1,2) combines score partials across the 4 slice lanes.
// Safe aliasing: each thread reads only its own (row x 16-dim slice) of QO
// into registers before the first barrier and writes the same slice at the
// end; slices are disjoint across threads/blocks.
__global__ __launch_bounds__(256)
void attn_kernel(float* __restrict__ QO, const float* __restrict__ K,
                 const float* __restrict__ V, const float* __restrict__ maskA)
{
    __shared__ float Ks[64][64];
    __shared__ float Vs[64][64];
    __shared__ float ms[64];
    const int b    = blockIdx.x;
    const int h    = blockIdx.y;
    const int qc   = blockIdx.z;           // 0..7
    const int tid  = threadIdx.x;
    const int qrow = qc * 64 + (tid >> 2); // 0..511
    const int sl   = (tid & 3) * 16;       // dim-slice base within head

    float* qptr = QO + (size_t)(b * SEQ + qrow) * DIM + h * DHEAD + sl;
    float q[16];
    #pragma unroll
    for (int d0 = 0; d0 < 16; d0 += 4) {
        float4 t4 = *reinterpret_cast<const float4*>(qptr + d0);
        q[d0] = t4.x; q[d0 + 1] = t4.y; q[d0 + 2] = t4.z; q[d0 + 3] = t4.w;
    }
    float o[16];
    #pragma unroll
    for (int d = 0; d < 16; d++) o[d] = 0.f;
    float mrun = -INFINITY, lrun = 0.f;

    for (int kt = 0; kt < SEQ; kt += 64) {
        __syncthreads();
        const float* kbase = K + (size_t)(b * SEQ + kt) * DIM + h * DHEAD;
        const float* vbase = V + (size_t)(b * SEQ + kt) * DIM + h * DHEAD;
        #pragma unroll
        for (int it = 0; it < 4; it++) {
            int f  = tid + it * 256;      // 0..1023
            int rr = f >> 4;              // 0..63
            int cc = (f & 15) << 2;       // 0..60
            *reinterpret_cast<float4*>(&Ks[rr][cc]) =
                *reinterpret_cast<const float4*>(kbase + (size_t)rr * DIM + cc);
            *reinterpret_cast<float4*>(&Vs[rr][cc]) =
                *reinterpret_cast<const float4*>(vbase + (size_t)rr * DIM + cc);
        }
        if (tid < 64) ms[tid] = maskA[b * SEQ + kt + tid];
        __syncthreads();

        for (int k0 = 0; k0 < 64; k0 += 16) {
            float s[16];
            #pragma unroll
            for (int j = 0; j < 16; j++) {
                const float* kr = &Ks[k0 + j][sl];
                float4 k0v = *reinterpret_cast<const float4*>(kr);
                float4 k1v = *reinterpret_cast<const float4*>(kr + 4);
                float4 k2v = *reinterpret_cast<const float4*>(kr + 8);
                float4 k3v = *reinterpret_cast<const float4*>(kr + 12);
                float p = q[0]  * k0v.x + q[1]  * k0v.y + q[2]  * k0v.z + q[3]  * k0v.w
                        + q[4]  * k1v.x + q[5]  * k1v.y + q[6]  * k1v.z + q[7]  * k1v.w
                        + q[8]  * k2v.x + q[9]  * k2v.y + q[10] * k2v.z + q[11] * k2v.w
                        + q[12] * k3v.x + q[13] * k3v.y + q[14] * k3v.z + q[15] * k3v.w;
                p += __shfl_xor(p, 1);
                p += __shfl_xor(p, 2);
                s[j] = (ms[k0 + j] != 0.f) ? p * 0.125f : -1e9f;
            }
            float tm = s[0];
            #pragma unroll
            for (int j = 1; j < 16; j++) tm = fmaxf(tm, s[j]);
            float mn = fmaxf(mrun, tm);
            float scale = __expf(mrun - mn);
            float ps = 0.f;
            #pragma unroll
            for (int j = 0; j < 16; j++) { s[j] = __expf(s[j] - mn); ps += s[j]; }
            lrun = lrun * scale + ps;
            #pragma unroll
            for (int d = 0; d < 16; d++) o[d] *= scale;
            #pragma unroll
            for (int j = 0; j < 16; j++) {
                const float* vr = &Vs[k0 + j][sl];
                float4 v0 = *reinterpret_cast<const float4*>(vr);
                float4 v1 = *reinterpret_cast<const float4*>(vr + 4);
                float4 v2 = *reinterpret_cast<const float4*>(vr + 8);
                float4 v3 = *reinterpret_cast<const float4*>(vr + 12);
                float sj = s[j];
                o[0]  += sj * v0.x;  o[1]  += sj * v0.y;  o[2]  += sj * v0.z;  o[3]  += sj * v0.w;
                o[4]  += sj * v1.x;  o[5]  += sj * v1.y;  o[6]  += sj * v1.z;  o[7]  += sj * v1.w;
                o[8]  += sj * v2.x;  o[9]  += sj * v2.y;  o[10] += sj * v2.z;  o[11] += sj * v2.w;
                o[12] += sj * v3.x;  o[13] += sj * v3.y;  o[14] += sj * v3.z;  o[15] += sj * v3.w;
            }
            mrun = mn;
        }
    }

    float inv = 1.0f / lrun;
    #pragma unroll
    for (int d0 = 0; d0 < 16; d0 += 4) {
        *reinterpret_cast<float4*>(qptr + d0) =
            make_float4(o[d0] * inv, o[d0 + 1] * inv, o[d0 + 2] * inv, o[d0 + 3] * inv);
    }
}

// ---------------- masked mean pool (one pass) ----------------
__global__ __launch_bounds__(512)
void pool_kernel(const float* __restrict__ h, const float* __restrict__ maskA,
                 float* __restrict__ pooled)
{
    int b = blockIdx.x;     // 0..31
    int d = threadIdx.x;    // 512
    float acc = 0.f, cnt = 0.f;
    for (int s = 0; s < SEQ; s++) {
        float mv = maskA[b * SEQ + s];
        acc += mv * h[((size_t)(b * SEQ + s)) * DIM + d];
        cnt += mv;
    }
    pooled[b * DIM + d] = acc / fmaxf(cnt, 1.f);
}

// ---------------- pooled @ Wp + bp -> henc rows [hoff, hoff+32) ------------
__global__ __launch_bounds__(512)
void proj_kernel(const float* __restrict__ pooled, const float* __restrict__ Wp,
                 const float* __restrict__ bp, float* __restrict__ henc, int hoff)
{
    int b = blockIdx.x;     // 0..31
    int j = threadIdx.x;    // 512
    __shared__ float p[DIM];
    p[j] = pooled[b * DIM + j];
    __syncthreads();
    float a0 = 0.f, a1 = 0.f, a2 = 0.f, a3 = 0.f;
    for (int d = 0; d < DIM; d += 4) {
        a0 += p[d]     * Wp[(size_t)d       * DIM + j];
        a1 += p[d + 1] * Wp[(size_t)(d + 1) * DIM + j];
        a2 += p[d + 2] * Wp[(size_t)(d + 2) * DIM + j];
        a3 += p[d + 3] * Wp[(size_t)(d + 3) * DIM + j];
    }
    henc[(size_t)(hoff + b) * DIM + j] = ((a0 + a1) + (a2 + a3)) + bp[j];
}

// ---------------- logits = concat(hH,hF) @ W_out + b_out ----------------
__global__ __launch_bounds__(256)
void logits_kernel(const float* __restrict__ henc, const float* __restrict__ Wout,
                   const float* __restrict__ bout, float* __restrict__ logits)
{
    int b = blockIdx.y;                       // 0..31
    int m = blockIdx.x * 256 + threadIdx.x;   // 0..1023
    __shared__ float hh[2 * DIM];
    for (int j = threadIdx.x; j < DIM; j += 256) {
        hh[j]       = henc[(size_t)b * DIM + j];
        hh[DIM + j] = henc[(size_t)(BATCH + b) * DIM + j];
    }
    __syncthreads();
    if (m < MM) {
        float a0 = 0.f, a1 = 0.f, a2 = 0.f, a3 = 0.f;
        for (int j = 0; j < 2 * DIM; j += 4) {
            a0 += hh[j]     * Wout[(size_t)j       * MM + m];
            a1 += hh[j + 1] * Wout[(size_t)(j + 1) * MM + m];
            a2 += hh[j + 2] * Wout[(size_t)(j + 2) * MM + m];
            a3 += hh[j + 3] * Wout[(size_t)(j + 3) * MM + m];
        }
        logits[b * MM + m] = ((a0 + a1) + (a2 + a3)) + bout[m];
    }
}

// ---------------- softmax + argmax ----------------
__global__ __launch_bounds__(256)
void smax_kernel(const float* __restrict__ logits, float* __restrict__ out)
{
    int b   = blockIdx.x;   // 0..31
    int tid = threadIdx.x;
    __shared__ float red[256];
    __shared__ int   redi[256];

    float v[4];
    float mx = -INFINITY;
    #pragma unroll
    for (int i = 0; i < 4; i++) {
        int m = tid + i * 256;
        if (m < MM) { v[i] = logits[b * MM + m]; mx = fmaxf(mx, v[i]); }
        else v[i] = -INFINITY;
    }
    red[tid] = mx; __syncthreads();
    for (int st = 128; st > 0; st >>= 1) {
        if (tid < st) red[tid] = fmaxf(red[tid], red[tid + st]);
        __syncthreads();
    }
    mx = red[0]; __syncthreads();

    float sum = 0.f;
    #pragma unroll
    for (int i = 0; i < 4; i++) {
        int m = tid + i * 256;
        if (m < MM) { v[i] = expf(v[i] - mx); sum += v[i]; }
    }
    red[tid] = sum; __syncthreads();
    for (int st = 128; st > 0; st >>= 1) {
        if (tid < st) red[tid] += red[tid + st];
        __syncthreads();
    }
    float inv = 1.0f / red[0]; __syncthreads();

    float bestv = -INFINITY; int besti = 0x7fffffff;
    #pragma unroll
    for (int i = 0; i < 4; i++) {
        int m = tid + i * 256;
        if (m < MM) {
            float lam = v[i] * inv;
            out[b * MM + m] = lam;
            if (lam > bestv) { bestv = lam; besti = m; }
        }
    }
    red[tid] = bestv; redi[tid] = besti; __syncthreads();
    for (int st = 128; st > 0; st >>= 1) {
        if (tid < st) {
            float ov = red[tid + st]; int oi = redi[tid + st];
            if (ov > red[tid] || (ov == red[tid] && oi < redi[tid])) {
                red[tid] = ov; redi[tid] = oi;
            }
        }
        __syncthreads();
    }
    if (tid == 0) out[BATCH * MM + b] = (float)redi[0];
}

// ---------------------------------------------------------------------------
extern "C" void kernel_launch(void* const* d_in, const int* in_sizes, int n_in,
                              void* d_out, int out_size, void* d_ws, size_t ws_size,
                              hipStream_t stream)
{
    const float* xH   = (const float*)d_in[0];
    const float* xF   = (const float*)d_in[1];
    const float* Wm   = (const float*)d_in[2];
    const float* Wt   = (const float*)d_in[3];
    const float* bt   = (const float*)d_in[4];
    const float* Wq   = (const float*)d_in[5];
    const float* Wk   = (const float*)d_in[6];
    const float* Wv   = (const float*)d_in[7];
    const float* Wo   = (const float*)d_in[8];
    const float* W1   = (const float*)d_in[9];
    const float* b1   = (const float*)d_in[10];
    const float* W2   = (const float*)d_in[11];
    const float* b2   = (const float*)d_in[12];
    const float* Wp   = (const float*)d_in[13];
    const float* bp   = (const float*)d_in[14];
    const float* Wout = (const float*)d_in[15];
    const float* bout = (const float*)d_in[16];
    float* out = (float*)d_out;

    float* ws     = (float*)d_ws;
    float* WmT    = ws;
    float* maskA  = ws + 524288;
    float* pooled = ws + 540672;
    float* henc   = ws + 557056;
    float* logits = ws + 589824;
    float* e      = ws + 1048576;
    float* QO     = e  + 8388608;
    float* Kb     = QO + 8388608;
    float* Vb     = Kb + 8388608;
    float* r      = Kb;   // FFN intermediate spans K+V (16,777,216 floats)

    // 1. transpose W_m (shared by both passes)
    transpose_wm<<<dim3(32, 16), 256, 0, stream>>>(Wm, WmT);

    for (int p = 0; p < 2; p++) {
        const float* x = (p == 0) ? xH : xF;
        // 2. embedding + mask
        embed_kernel<<<dim3(ROWS), 256, 0, stream>>>(x, WmT, Wt, bt, e, maskA);
        // 3. Q,K,V projections: [16384,512] @ [512,512]
        sgemm<false, false, false><<<dim3(4, 128), 256, 0, stream>>>(e, Wq, nullptr, nullptr, QO, ROWS, DIM, DIM);
        sgemm<false, false, false><<<dim3(4, 128), 256, 0, stream>>>(e, Wk, nullptr, nullptr, Kb, ROWS, DIM, DIM);
        sgemm<false, false, false><<<dim3(4, 128), 256, 0, stream>>>(e, Wv, nullptr, nullptr, Vb, ROWS, DIM, DIM);
        // 4. fused attention, O overwrites Q
        attn_kernel<<<dim3(BATCH, NHEAD, 8), 256, 0, stream>>>(QO, Kb, Vb, maskA);
        // 5. h = e + O @ Wo  (in-place residual into e)
        sgemm<false, false, true><<<dim3(4, 128), 256, 0, stream>>>(QO, Wo, nullptr, e, e, ROWS, DIM, DIM);
        // 6. FFN in 2 row-chunks of 8192 (r reuses K+V span)
        for (int c = 0; c < 2; c++) {
            float* hc = e + (size_t)c * 8192 * DIM;
            sgemm<true, true, false><<<dim3(DFFN / 128, 64), 256, 0, stream>>>(
                hc, W1, b1, nullptr, r, 8192, DFFN, DIM);
            sgemm<true, false, true><<<dim3(DIM / 128, 64), 256, 0, stream>>>(
                r, W2, b2, hc, hc, 8192, DIM, DFFN);
        }
        // 7. masked mean pool
        pool_kernel<<<dim3(BATCH), 512, 0, stream>>>(e, maskA, pooled);
        // 8. pooled @ Wp + bp -> henc rows [32p, 32p+32)
        proj_kernel<<<dim3(BATCH), 512, 0, stream>>>(pooled, Wp, bp, henc, p * BATCH);
    }

    // 9. logits
    logits_kernel<<<dim3(4, BATCH), 256, 0, stream>>>(henc, Wout, bout, logits);
    // 10. softmax + argmax -> d_out
    smax_kernel<<<dim3(BATCH), 256, 0, stream>>>(logits, out);
}

// Round 4
// 1828.953 us; speedup vs baseline: 2.4768x; 1.9154x over previous
//
#include <hip/hip_runtime.h>
#include <math.h>

// Problem constants
#define BATCH 32     // per-pass batch (H pass then F pass)
#define SEQ  512
#define DIM  512
#define MM   1000
#define NHEAD 8
#define DHEAD 64
#define DFFN 2048
#define ROWS (BATCH * SEQ)   // 16384 rows per pass

typedef __attribute__((ext_vector_type(8))) short short8;
typedef __attribute__((ext_vector_type(4))) float f32x4;

__device__ __forceinline__ ushort f2bf(float x) {
    unsigned u = __builtin_bit_cast(unsigned, x);
    unsigned r = (u + 0x7FFFu + ((u >> 16) & 1u)) >> 16;
    return (ushort)r;
}
__device__ __forceinline__ float bf2f(ushort h) {
    unsigned u = ((unsigned)h) << 16;
    return __builtin_bit_cast(float, u);
}

// ---------------------------------------------------------------------------
// ws layout (float32-slot offsets) — total 32,636,928 slots = 130.5 MB
// ---------------------------------------------------------------------------
constexpr size_t OFF_WMT  = 0;         // fp32 [1000][512]
constexpr size_t OFF_MASK = 524288;    // fp32 [16384]
constexpr size_t OFF_POOL = 540672;    // fp32 [32][512]
constexpr size_t OFF_HENC = 557056;    // fp32 [64][512]
constexpr size_t OFF_LOG  = 589824;    // fp32 [32][1000]
constexpr size_t OFF_WQTH = 655360;    // bf16 [512][512]   (each 131072 slots)
constexpr size_t OFF_WKTH = 786432;
constexpr size_t OFF_WVTH = 917504;
constexpr size_t OFF_WOTH = 1048576;
constexpr size_t OFF_W1TH = 1179648;   // bf16 [2048][512]  (524288 slots)
constexpr size_t OFF_W1TL = 1703936;
constexpr size_t OFF_W2TH = 2228224;   // bf16 [512][2048]
constexpr size_t OFF_W2TL = 2752512;
constexpr size_t OFF_EHI  = 3276800;   // bf16 [16384][512] (4194304 slots)
constexpr size_t OFF_ELO  = 7471104;
constexpr size_t OFF_QB   = 11665408;  // bf16 Q -> O -> h'_hi
constexpr size_t OFF_KB   = 15859712;  // bf16 K -> h'_lo
constexpr size_t OFF_VB   = 20054016;  // bf16 V
constexpr size_t OFF_RHI  = 24248320;  // bf16 [16384][512] FFN chunk
constexpr size_t OFF_RLO  = 28442624;

// ---------------- transpose W_m [512,1000] -> WmT [1000,512] (fp32) --------
__global__ __launch_bounds__(256)
void transpose_wm(const float* __restrict__ Wm, float* __restrict__ WmT)
{
    __shared__ float tile[32][33];
    int tx = threadIdx.x & 31;
    int ty = threadIdx.x >> 5;
    int mx = blockIdx.x * 32;
    int dy = blockIdx.y * 32;
    for (int i = ty; i < 32; i += 8) {
        int d = dy + i, m = mx + tx;
        tile[i][tx] = (m < MM) ? Wm[(size_t)d * MM + m] : 0.f;
    }
    __syncthreads();
    for (int i = ty; i < 32; i += 8) {
        int m = mx + i, d = dy + tx;
        if (m < MM) WmT[(size_t)m * DIM + d] = tile[tx][i];
    }
}

// ---------------- split+transpose weight: W[K,N] -> WT_h/WT_l [N,K] bf16 ---
template<bool LO>
__global__ __launch_bounds__(256)
void split_wT(const float* __restrict__ W, ushort* __restrict__ Th,
              ushort* __restrict__ Tl, int K, int N)
{
    __shared__ float tile[32][33];
    int tx = threadIdx.x & 31;
    int ty = threadIdx.x >> 5;
    int n0 = blockIdx.x * 32;
    int k0 = blockIdx.y * 32;
    for (int i = ty; i < 32; i += 8)
        tile[i][tx] = W[(size_t)(k0 + i) * N + n0 + tx];
    __syncthreads();
    for (int i = ty; i < 32; i += 8) {
        int n = n0 + i, k = k0 + tx;
        float x = tile[tx][i];
        ushort h = f2bf(x);
        Th[(size_t)n * K + k] = h;
        if (LO) Tl[(size_t)n * K + k] = f2bf(x - bf2f(h));
    }
}

// ---------------- embedding + mask -> e_hi/e_lo bf16 ----------------------
__global__ __launch_bounds__(256)
void embed_kernel(const float* __restrict__ x,
                  const float* __restrict__ WmT, const float* __restrict__ Wt,
                  const float* __restrict__ bt,
                  ushort* __restrict__ ehi, ushort* __restrict__ elo,
                  float* __restrict__ maskA)
{
    int bs = blockIdx.x;
    const float* xp = x + (size_t)bs * 2;
    float t   = xp[0];
    float mkf = xp[1];
    int   mk  = (int)fminf(fmaxf(mkf, 0.f), (float)(MM - 1));
    bool  valid = (t >= 0.f);
    if (threadIdx.x == 0) maskA[bs] = valid ? 1.f : 0.f;
    const float* wrow = WmT + (size_t)mk * DIM;
    size_t base = (size_t)bs * DIM;
    for (int d = threadIdx.x; d < DIM; d += 256) {
        float v = 0.5f * wrow[d] + 0.5f * (Wt[d] * t + bt[d]);
        v = valid ? v : 0.f;
        ushort h = f2bf(v);
        ehi[base + d] = h;
        elo[base + d] = f2bf(v - bf2f(h));
    }
}

// ---------------- bf16 MFMA GEMM ------------------------------------------
// C[M,N](bf16 out, optional hi/lo pair) = sum_seg A_seg @ B_seg^T  [+bias][+res][relu]
// A: [M,K] bf16 row-major (lda). B: stored TRANSPOSED [N,K] bf16 row-major (ldb).
// SEGS=1: A0*B0. SEGS=3: A0*B0 + A1*B0 + A0*B1  (hi/lo split-3).
// 128x128 tile, BK=64, 256 threads = 4 waves, each wave 64x64 (4x4 frags of
// 16x16x32). LDS XOR-swizzled: slot' = slot ^ (row&7)  (conflict-free reads).
template<int SEGS, bool BIAS, bool RELU, bool RES, bool PAIR>
__global__ __launch_bounds__(256)
void gemm_bf16(const ushort* __restrict__ A0, const ushort* __restrict__ A1,
               const ushort* __restrict__ B0, const ushort* __restrict__ B1,
               const float* __restrict__ bias,
               const ushort* __restrict__ Rh, const ushort* __restrict__ Rl,
               ushort* __restrict__ Oh, ushort* __restrict__ Ol,
               int Md, int Nd, int Kd, int lda, int ldb)
{
    __shared__ __align__(16) ushort As[128 * 64];
    __shared__ __align__(16) ushort Bs[128 * 64];
    char* AsB = (char*)As;
    char* BsB = (char*)Bs;
    const int tid = threadIdx.x;
    const int w = tid >> 6, l = tid & 63;
    const int wr = w >> 1, wc = w & 1;
    const int l15 = l & 15, lg = l >> 4;
    const int row0 = blockIdx.y * 128;
    const int col0 = blockIdx.x * 128;
    const int srow = l >> 3, slot = l & 7;

    f32x4 acc[4][4];
    #pragma unroll
    for (int m = 0; m < 4; m++)
        #pragma unroll
        for (int n = 0; n < 4; n++)
            acc[m][n] = (f32x4){0.f, 0.f, 0.f, 0.f};

    for (int seg = 0; seg < SEGS; ++seg) {
        const ushort* Ap = (seg == 1) ? A1 : A0;
        const ushort* Bp = (seg == 2) ? B1 : B0;
        for (int kt = 0; kt < Kd; kt += 64) {
            __syncthreads();
            // stage A-tile [128][64] and B-tile [128][64] (BT rows = out cols)
            #pragma unroll
            for (int r = 0; r < 4; ++r) {
                int row = w * 32 + r * 8 + srow;
                uint4 va = *reinterpret_cast<const uint4*>(
                    Ap + (size_t)(row0 + row) * lda + kt + slot * 8);
                uint4 vb = *reinterpret_cast<const uint4*>(
                    Bp + (size_t)(col0 + row) * ldb + kt + slot * 8);
                int ds = ((slot ^ (row & 7)) << 4) + row * 128;
                *reinterpret_cast<uint4*>(AsB + ds) = va;
                *reinterpret_cast<uint4*>(BsB + ds) = vb;
            }
            __syncthreads();
            #pragma unroll
            for (int ks = 0; ks < 2; ++ks) {
                const int g = ks * 4 + lg;       // k-8-group 0..7 within BK
                short8 af[4], bfr[4];
                #pragma unroll
                for (int m = 0; m < 4; ++m) {
                    int row = wr * 64 + m * 16 + l15;
                    af[m] = *reinterpret_cast<const short8*>(
                        AsB + row * 128 + ((g ^ (row & 7)) << 4));
                }
                #pragma unroll
                for (int n = 0; n < 4; ++n) {
                    int row = wc * 64 + n * 16 + l15;
                    bfr[n] = *reinterpret_cast<const short8*>(
                        BsB + row * 128 + ((g ^ (row & 7)) << 4));
                }
                #pragma unroll
                for (int m = 0; m < 4; ++m)
                    #pragma unroll
                    for (int n = 0; n < 4; ++n)
                        acc[m][n] = __builtin_amdgcn_mfma_f32_16x16x32_bf16(
                            af[m], bfr[n], acc[m][n], 0, 0, 0);
            }
        }
    }

    // epilogue: D row=(lane>>4)*4+j, col=lane&15 within each 16x16 frag
    #pragma unroll
    for (int m = 0; m < 4; ++m) {
        #pragma unroll
        for (int n = 0; n < 4; ++n) {
            int col = col0 + wc * 64 + n * 16 + l15;
            float bia = 0.f;
            if (BIAS) bia = bias[col];
            #pragma unroll
            for (int j = 0; j < 4; ++j) {
                int row = row0 + wr * 64 + m * 16 + lg * 4 + j;
                size_t idx = (size_t)row * Nd + col;
                float v = acc[m][n][j] + bia;
                if (RES)  v += bf2f(Rh[idx]) + bf2f(Rl[idx]);
                if (RELU) v = fmaxf(v, 0.f);
                ushort hv = f2bf(v);
                Oh[idx] = hv;
                if (PAIR) Ol[idx] = f2bf(v - bf2f(hv));
            }
        }
    }
}

// ---------------- fused flash attention (fp32 core, bf16 I/O) --------------
// grid (BATCH, NHEAD, 8); 256 threads; 4 threads per q-row (16-dim slices).
// O (bf16) written in place over Q: each thread touches only its own slice.
__global__ __launch_bounds__(256)
void attn_kernel(ushort* __restrict__ QO, const ushort* __restrict__ K,
                 const ushort* __restrict__ V, const float* __restrict__ maskA)
{
    __shared__ float Ks[64][64];
    __shared__ float Vs[64][64];
    __shared__ float ms[64];
    const int b    = blockIdx.x;
    const int h    = blockIdx.y;
    const int qc   = blockIdx.z;
    const int tid  = threadIdx.x;
    const int qrow = qc * 64 + (tid >> 2);
    const int sl   = (tid & 3) * 16;

    ushort* qptr = QO + (size_t)(b * SEQ + qrow) * DIM + h * DHEAD + sl;
    float q[16];
    {
        union { uint4 u; ushort s[8]; } a, c;
        a.u = *reinterpret_cast<const uint4*>(qptr);
        c.u = *reinterpret_cast<const uint4*>(qptr + 8);
        #pragma unroll
        for (int j = 0; j < 8; j++) { q[j] = bf2f(a.s[j]); q[8 + j] = bf2f(c.s[j]); }
    }
    float o[16];
    #pragma unroll
    for (int d = 0; d < 16; d++) o[d] = 0.f;
    float mrun = -INFINITY, lrun = 0.f;

    for (int kt = 0; kt < SEQ; kt += 64) {
        __syncthreads();
        const ushort* kbase = K + (size_t)(b * SEQ + kt) * DIM + h * DHEAD;
        const ushort* vbase = V + (size_t)(b * SEQ + kt) * DIM + h * DHEAD;
        #pragma unroll
        for (int it = 0; it < 2; ++it) {
            int idx = tid + it * 256;        // 0..511
            int rr  = idx >> 3;
            int c8  = (idx & 7) * 8;
            union { uint4 u; ushort s[8]; } kv, vv;
            kv.u = *reinterpret_cast<const uint4*>(kbase + (size_t)rr * DIM + c8);
            vv.u = *reinterpret_cast<const uint4*>(vbase + (size_t)rr * DIM + c8);
            *reinterpret_cast<float4*>(&Ks[rr][c8]) =
                make_float4(bf2f(kv.s[0]), bf2f(kv.s[1]), bf2f(kv.s[2]), bf2f(kv.s[3]));
            *reinterpret_cast<float4*>(&Ks[rr][c8 + 4]) =
                make_float4(bf2f(kv.s[4]), bf2f(kv.s[5]), bf2f(kv.s[6]), bf2f(kv.s[7]));
            *reinterpret_cast<float4*>(&Vs[rr][c8]) =
                make_float4(bf2f(vv.s[0]), bf2f(vv.s[1]), bf2f(vv.s[2]), bf2f(vv.s[3]));
            *reinterpret_cast<float4*>(&Vs[rr][c8 + 4]) =
                make_float4(bf2f(vv.s[4]), bf2f(vv.s[5]), bf2f(vv.s[6]), bf2f(vv.s[7]));
        }
        if (tid < 64) ms[tid] = maskA[b * SEQ + kt + tid];
        __syncthreads();

        for (int k0 = 0; k0 < 64; k0 += 16) {
            float s[16];
            #pragma unroll
            for (int j = 0; j < 16; j++) {
                const float* kr = &Ks[k0 + j][sl];
                float4 k0v = *reinterpret_cast<const float4*>(kr);
                float4 k1v = *reinterpret_cast<const float4*>(kr + 4);
                float4 k2v = *reinterpret_cast<const float4*>(kr + 8);
                float4 k3v = *reinterpret_cast<const float4*>(kr + 12);
                float p = q[0]  * k0v.x + q[1]  * k0v.y + q[2]  * k0v.z + q[3]  * k0v.w
                        + q[4]  * k1v.x + q[5]  * k1v.y + q[6]  * k1v.z + q[7]  * k1v.w
                        + q[8]  * k2v.x + q[9]  * k2v.y + q[10] * k2v.z + q[11] * k2v.w
                        + q[12] * k3v.x + q[13] * k3v.y + q[14] * k3v.z + q[15] * k3v.w;
                p += __shfl_xor(p, 1);
                p += __shfl_xor(p, 2);
                s[j] = (ms[k0 + j] != 0.f) ? p * 0.125f : -1e9f;
            }
            float tm = s[0];
            #pragma unroll
            for (int j = 1; j < 16; j++) tm = fmaxf(tm, s[j]);
            float mn = fmaxf(mrun, tm);
            float scale = __expf(mrun - mn);
            float ps = 0.f;
            #pragma unroll
            for (int j = 0; j < 16; j++) { s[j] = __expf(s[j] - mn); ps += s[j]; }
            lrun = lrun * scale + ps;
            #pragma unroll
            for (int d = 0; d < 16; d++) o[d] *= scale;
            #pragma unroll
            for (int j = 0; j < 16; j++) {
                const float* vr = &Vs[k0 + j][sl];
                float4 v0 = *reinterpret_cast<const float4*>(vr);
                float4 v1 = *reinterpret_cast<const float4*>(vr + 4);
                float4 v2 = *reinterpret_cast<const float4*>(vr + 8);
                float4 v3 = *reinterpret_cast<const float4*>(vr + 12);
                float sj = s[j];
                o[0]  += sj * v0.x;  o[1]  += sj * v0.y;  o[2]  += sj * v0.z;  o[3]  += sj * v0.w;
                o[4]  += sj * v1.x;  o[5]  += sj * v1.y;  o[6]  += sj * v1.z;  o[7]  += sj * v1.w;
                o[8]  += sj * v2.x;  o[9]  += sj * v2.y;  o[10] += sj * v2.z;  o[11] += sj * v2.w;
                o[12] += sj * v3.x;  o[13] += sj * v3.y;  o[14] += sj * v3.z;  o[15] += sj * v3.w;
            }
            mrun = mn;
        }
    }

    float inv = 1.0f / lrun;
    union { uint4 u; ushort s[8]; } p0, p1;
    #pragma unroll
    for (int j = 0; j < 8; j++) {
        p0.s[j] = f2bf(o[j] * inv);
        p1.s[j] = f2bf(o[8 + j] * inv);
    }
    *reinterpret_cast<uint4*>(qptr)     = p0.u;
    *reinterpret_cast<uint4*>(qptr + 8) = p1.u;
}

// ---------------- masked mean pool (reads bf16 hi/lo h) --------------------
__global__ __launch_bounds__(512)
void pool_kernel(const ushort* __restrict__ hh, const ushort* __restrict__ hl,
                 const float* __restrict__ maskA, float* __restrict__ pooled)
{
    int b = blockIdx.x;
    int d = threadIdx.x;
    float acc = 0.f, cnt = 0.f;
    for (int s = 0; s < SEQ; s++) {
        float mv = maskA[b * SEQ + s];
        size_t idx = ((size_t)(b * SEQ + s)) * DIM + d;
        acc += mv * (bf2f(hh[idx]) + bf2f(hl[idx]));
        cnt += mv;
    }
    pooled[b * DIM + d] = acc / fmaxf(cnt, 1.f);
}

// ---------------- pooled @ Wp + bp -> henc rows [hoff, hoff+32) ------------
__global__ __launch_bounds__(512)
void proj_kernel(const float* __restrict__ pooled, const float* __restrict__ Wp,
                 const float* __restrict__ bp, float* __restrict__ henc, int hoff)
{
    int b = blockIdx.x;
    int j = threadIdx.x;
    __shared__ float p[DIM];
    p[j] = pooled[b * DIM + j];
    __syncthreads();
    float a0 = 0.f, a1 = 0.f, a2 = 0.f, a3 = 0.f;
    for (int d = 0; d < DIM; d += 4) {
        a0 += p[d]     * Wp[(size_t)d       * DIM + j];
        a1 += p[d + 1] * Wp[(size_t)(d + 1) * DIM + j];
        a2 += p[d + 2] * Wp[(size_t)(d + 2) * DIM + j];
        a3 += p[d + 3] * Wp[(size_t)(d + 3) * DIM + j];
    }
    henc[(size_t)(hoff + b) * DIM + j] = ((a0 + a1) + (a2 + a3)) + bp[j];
}

// ---------------- logits = concat(hH,hF) @ W_out + b_out -------------------
__global__ __launch_bounds__(256)
void logits_kernel(const float* __restrict__ henc, const float* __restrict__ Wout,
                   const float* __restrict__ bout, float* __restrict__ logits)
{
    int b = blockIdx.y;
    int m = blockIdx.x * 256 + threadIdx.x;
    __shared__ float hh[2 * DIM];
    for (int j = threadIdx.x; j < DIM; j += 256) {
        hh[j]       = henc[(size_t)b * DIM + j];
        hh[DIM + j] = henc[(size_t)(BATCH + b) * DIM + j];
    }
    __syncthreads();
    if (m < MM) {
        float a0 = 0.f, a1 = 0.f, a2 = 0.f, a3 = 0.f;
        for (int j = 0; j < 2 * DIM; j += 4) {
            a0 += hh[j]     * Wout[(size_t)j       * MM + m];
            a1 += hh[j + 1] * Wout[(size_t)(j + 1) * MM + m];
            a2 += hh[j + 2] * Wout[(size_t)(j + 2) * MM + m];
            a3 += hh[j + 3] * Wout[(size_t)(j + 3) * MM + m];
        }
        logits[b * MM + m] = ((a0 + a1) + (a2 + a3)) + bout[m];
    }
}

// ---------------- softmax + argmax ----------------
__global__ __launch_bounds__(256)
void smax_kernel(const float* __restrict__ logits, float* __restrict__ out)
{
    int b   = blockIdx.x;
    int tid = threadIdx.x;
    __shared__ float red[256];
    __shared__ int   redi[256];

    float v[4];
    float mx = -INFINITY;
    #pragma unroll
    for (int i = 0; i < 4; i++) {
        int m = tid + i * 256;
        if (m < MM) { v[i] = logits[b * MM + m]; mx = fmaxf(mx, v[i]); }
        else v[i] = -INFINITY;
    }
    red[tid] = mx; __syncthreads();
    for (int st = 128; st > 0; st >>= 1) {
        if (tid < st) red[tid] = fmaxf(red[tid], red[tid + st]);
        __syncthreads();
    }
    mx = red[0]; __syncthreads();

    float sum = 0.f;
    #pragma unroll
    for (int i = 0; i < 4; i++) {
        int m = tid + i * 256;
        if (m < MM) { v[i] = expf(v[i] - mx); sum += v[i]; }
    }
    red[tid] = sum; __syncthreads();
    for (int st = 128; st > 0; st >>= 1) {
        if (tid < st) red[tid] += red[tid + st];
        __syncthreads();
    }
    float inv = 1.0f / red[0]; __syncthreads();

    float bestv = -INFINITY; int besti = 0x7fffffff;
    #pragma unroll
    for (int i = 0; i < 4; i++) {
        int m = tid + i * 256;
        if (m < MM) {
            float lam = v[i] * inv;
            out[b * MM + m] = lam;
            if (lam > bestv) { bestv = lam; besti = m; }
        }
    }
    red[tid] = bestv; redi[tid] = besti; __syncthreads();
    for (int st = 128; st > 0; st >>= 1) {
        if (tid < st) {
            float ov = red[tid + st]; int oi = redi[tid + st];
            if (ov > red[tid] || (ov == red[tid] && oi < redi[tid])) {
                red[tid] = ov; redi[tid] = oi;
            }
        }
        __syncthreads();
    }
    if (tid == 0) out[BATCH * MM + b] = (float)redi[0];
}

// ---------------------------------------------------------------------------
extern "C" void kernel_launch(void* const* d_in, const int* in_sizes, int n_in,
                              void* d_out, int out_size, void* d_ws, size_t ws_size,
                              hipStream_t stream)
{
    const float* xH   = (const float*)d_in[0];
    const float* xF   = (const float*)d_in[1];
    const float* Wm   = (const float*)d_in[2];
    const float* Wt   = (const float*)d_in[3];
    const float* bt   = (const float*)d_in[4];
    const float* Wq   = (const float*)d_in[5];
    const float* Wk   = (const float*)d_in[6];
    const float* Wv   = (const float*)d_in[7];
    const float* Wo   = (const float*)d_in[8];
    const float* W1   = (const float*)d_in[9];
    const float* b1   = (const float*)d_in[10];
    const float* W2   = (const float*)d_in[11];
    const float* b2   = (const float*)d_in[12];
    const float* Wp   = (const float*)d_in[13];
    const float* bp   = (const float*)d_in[14];
    const float* Wout = (const float*)d_in[15];
    const float* bout = (const float*)d_in[16];
    float* out = (float*)d_out;

    float* ws     = (float*)d_ws;
    float*  WmT    = ws + OFF_WMT;
    float*  maskA  = ws + OFF_MASK;
    float*  pooled = ws + OFF_POOL;
    float*  henc   = ws + OFF_HENC;
    float*  logits = ws + OFF_LOG;
    ushort* WqTh   = (ushort*)(ws + OFF_WQTH);
    ushort* WkTh   = (ushort*)(ws + OFF_WKTH);
    ushort* WvTh   = (ushort*)(ws + OFF_WVTH);
    ushort* WoTh   = (ushort*)(ws + OFF_WOTH);
    ushort* W1Th   = (ushort*)(ws + OFF_W1TH);
    ushort* W1Tl   = (ushort*)(ws + OFF_W1TL);
    ushort* W2Th   = (ushort*)(ws + OFF_W2TH);
    ushort* W2Tl   = (ushort*)(ws + OFF_W2TL);
    ushort* ehi    = (ushort*)(ws + OFF_EHI);
    ushort* elo    = (ushort*)(ws + OFF_ELO);
    ushort* Qb     = (ushort*)(ws + OFF_QB);   // Q -> O -> h'_hi
    ushort* Kb     = (ushort*)(ws + OFF_KB);   // K -> h'_lo
    ushort* Vb     = (ushort*)(ws + OFF_VB);
    ushort* rhi    = (ushort*)(ws + OFF_RHI);
    ushort* rlo    = (ushort*)(ws + OFF_RLO);

    // ---- setup (shared by both passes) ----
    transpose_wm<<<dim3(32, 16), 256, 0, stream>>>(Wm, WmT);
    split_wT<false><<<dim3(16, 16), 256, 0, stream>>>(Wq, WqTh, nullptr, DIM, DIM);
    split_wT<false><<<dim3(16, 16), 256, 0, stream>>>(Wk, WkTh, nullptr, DIM, DIM);
    split_wT<false><<<dim3(16, 16), 256, 0, stream>>>(Wv, WvTh, nullptr, DIM, DIM);
    split_wT<false><<<dim3(16, 16), 256, 0, stream>>>(Wo, WoTh, nullptr, DIM, DIM);
    split_wT<true ><<<dim3(64, 16), 256, 0, stream>>>(W1, W1Th, W1Tl, DIM, DFFN);
    split_wT<true ><<<dim3(16, 64), 256, 0, stream>>>(W2, W2Th, W2Tl, DFFN, DIM);

    for (int p = 0; p < 2; p++) {
        const float* x = (p == 0) ? xH : xF;
        // embedding -> e hi/lo + mask
        embed_kernel<<<dim3(ROWS), 256, 0, stream>>>(x, WmT, Wt, bt, ehi, elo, maskA);
        // Q,K,V = e_hi @ W{q,k,v}  (single bf16; 1%-branch precision is enough)
        gemm_bf16<1,false,false,false,false><<<dim3(4, 128), 256, 0, stream>>>(
            ehi, nullptr, WqTh, nullptr, nullptr, nullptr, nullptr,
            Qb, nullptr, ROWS, DIM, DIM, DIM, DIM);
        gemm_bf16<1,false,false,false,false><<<dim3(4, 128), 256, 0, stream>>>(
            ehi, nullptr, WkTh, nullptr, nullptr, nullptr, nullptr,
            Kb, nullptr, ROWS, DIM, DIM, DIM, DIM);
        gemm_bf16<1,false,false,false,false><<<dim3(4, 128), 256, 0, stream>>>(
            ehi, nullptr, WvTh, nullptr, nullptr, nullptr, nullptr,
            Vb, nullptr, ROWS, DIM, DIM, DIM, DIM);
        // attention (fp32 core), O overwrites Q
        attn_kernel<<<dim3(BATCH, NHEAD, 8), 256, 0, stream>>>(Qb, Kb, Vb, maskA);
        // h = e + O @ Wo   (res from e hi/lo, out hi/lo in place over e)
        gemm_bf16<1,false,false,true,true><<<dim3(4, 128), 256, 0, stream>>>(
            Qb, nullptr, WoTh, nullptr, nullptr, ehi, elo,
            ehi, elo, ROWS, DIM, DIM, DIM, DIM);
        // FFN over 4 DFF-chunks of 512; split-3 both GEMMs; accumulate into h'
        // (h' lives in dead Q/K regions so pristine h stays for every chunk)
        for (int nc = 0; nc < 4; nc++) {
            gemm_bf16<3,true,true,false,true><<<dim3(4, 128), 256, 0, stream>>>(
                ehi, elo, W1Th + (size_t)nc * 512 * DIM, W1Tl + (size_t)nc * 512 * DIM,
                b1 + nc * 512, nullptr, nullptr,
                rhi, rlo, ROWS, 512, DIM, DIM, DIM);
            if (nc == 0)
                gemm_bf16<3,true,false,true,true><<<dim3(4, 128), 256, 0, stream>>>(
                    rhi, rlo, W2Th + nc * 512, W2Tl + nc * 512,
                    b2, ehi, elo,
                    Qb, Kb, ROWS, DIM, 512, 512, DFFN);
            else
                gemm_bf16<3,false,false,true,true><<<dim3(4, 128), 256, 0, stream>>>(
                    rhi, rlo, W2Th + nc * 512, W2Tl + nc * 512,
                    nullptr, Qb, Kb,
                    Qb, Kb, ROWS, DIM, 512, 512, DFFN);
        }
        // masked mean pool over h' (hi in Qb, lo in Kb)
        pool_kernel<<<dim3(BATCH), 512, 0, stream>>>(Qb, Kb, maskA, pooled);
        // pooled @ Wp + bp
        proj_kernel<<<dim3(BATCH), 512, 0, stream>>>(pooled, Wp, bp, henc, p * BATCH);
    }

    // head
    logits_kernel<<<dim3(4, BATCH), 256, 0, stream>>>(henc, Wout, bout, logits);
    smax_kernel<<<dim3(BATCH), 256, 0, stream>>>(logits, out);
}

// Round 5
// 1094.597 us; speedup vs baseline: 4.1385x; 1.6709x over previous
//
#include <hip/hip_runtime.h>
#include <math.h>

// Problem constants
#define BATCH 32     // per-pass batch (H pass then F pass)
#define SEQ  512
#define DIM  512
#define MM   1000
#define NHEAD 8
#define DHEAD 64
#define DFFN 2048
#define ROWS (BATCH * SEQ)   // 16384 rows per pass

typedef __attribute__((ext_vector_type(8))) short short8;
typedef __attribute__((ext_vector_type(4))) float f32x4;

__device__ __forceinline__ ushort f2bf(float x) {
    unsigned u = __builtin_bit_cast(unsigned, x);
    unsigned r = (u + 0x7FFFu + ((u >> 16) & 1u)) >> 16;
    return (ushort)r;
}
__device__ __forceinline__ float bf2f(ushort h) {
    unsigned u = ((unsigned)h) << 16;
    return __builtin_bit_cast(float, u);
}

// ---------------------------------------------------------------------------
// ws layout (float32-slot offsets) — total 32,636,928 slots = 130.5 MB
// ---------------------------------------------------------------------------
constexpr size_t OFF_WMT  = 0;         // fp32 [1000][512]
constexpr size_t OFF_MASK = 524288;    // fp32 [16384]
constexpr size_t OFF_POOL = 540672;    // fp32 [32][512]
constexpr size_t OFF_HENC = 557056;    // fp32 [64][512]
constexpr size_t OFF_LOG  = 589824;    // fp32 [32][1000]
constexpr size_t OFF_WQTH = 655360;    // bf16 [512][512]   (each 131072 slots)
constexpr size_t OFF_WKTH = 786432;
constexpr size_t OFF_WVTH = 917504;
constexpr size_t OFF_WOTH = 1048576;
constexpr size_t OFF_W1TH = 1179648;   // bf16 [2048][512]  (524288 slots)
constexpr size_t OFF_W1TL = 1703936;
constexpr size_t OFF_W2TH = 2228224;   // bf16 [512][2048]
constexpr size_t OFF_W2TL = 2752512;
constexpr size_t OFF_EHI  = 3276800;   // bf16 [16384][512] (4194304 slots)
constexpr size_t OFF_ELO  = 7471104;
constexpr size_t OFF_QB   = 11665408;  // bf16 Q -> O -> h'_hi
constexpr size_t OFF_KB   = 15859712;  // bf16 K -> h'_lo
constexpr size_t OFF_VB   = 20054016;  // bf16 V^T per batch [b][512 dh][512 s]
constexpr size_t OFF_RHI  = 24248320;  // bf16 [16384][512] FFN chunk
constexpr size_t OFF_RLO  = 28442624;

// ---------------- transpose W_m [512,1000] -> WmT [1000,512] (fp32) --------
__global__ __launch_bounds__(256)
void transpose_wm(const float* __restrict__ Wm, float* __restrict__ WmT)
{
    __shared__ float tile[32][33];
    int tx = threadIdx.x & 31;
    int ty = threadIdx.x >> 5;
    int mx = blockIdx.x * 32;
    int dy = blockIdx.y * 32;
    for (int i = ty; i < 32; i += 8) {
        int d = dy + i, m = mx + tx;
        tile[i][tx] = (m < MM) ? Wm[(size_t)d * MM + m] : 0.f;
    }
    __syncthreads();
    for (int i = ty; i < 32; i += 8) {
        int m = mx + i, d = dy + tx;
        if (m < MM) WmT[(size_t)m * DIM + d] = tile[tx][i];
    }
}

// ---------------- split+transpose weight: W[K,N] -> WT_h/WT_l [N,K] bf16 ---
template<bool LO>
__global__ __launch_bounds__(256)
void split_wT(const float* __restrict__ W, ushort* __restrict__ Th,
              ushort* __restrict__ Tl, int K, int N)
{
    __shared__ float tile[32][33];
    int tx = threadIdx.x & 31;
    int ty = threadIdx.x >> 5;
    int n0 = blockIdx.x * 32;
    int k0 = blockIdx.y * 32;
    for (int i = ty; i < 32; i += 8)
        tile[i][tx] = W[(size_t)(k0 + i) * N + n0 + tx];
    __syncthreads();
    for (int i = ty; i < 32; i += 8) {
        int n = n0 + i, k = k0 + tx;
        float x = tile[tx][i];
        ushort h = f2bf(x);
        Th[(size_t)n * K + k] = h;
        if (LO) Tl[(size_t)n * K + k] = f2bf(x - bf2f(h));
    }
}

// ---------------- embedding + mask -> e_hi/e_lo bf16 ----------------------
__global__ __launch_bounds__(256)
void embed_kernel(const float* __restrict__ x,
                  const float* __restrict__ WmT, const float* __restrict__ Wt,
                  const float* __restrict__ bt,
                  ushort* __restrict__ ehi, ushort* __restrict__ elo,
                  float* __restrict__ maskA)
{
    int bs = blockIdx.x;
    const float* xp = x + (size_t)bs * 2;
    float t   = xp[0];
    float mkf = xp[1];
    int   mk  = (int)fminf(fmaxf(mkf, 0.f), (float)(MM - 1));
    bool  valid = (t >= 0.f);
    if (threadIdx.x == 0) maskA[bs] = valid ? 1.f : 0.f;
    const float* wrow = WmT + (size_t)mk * DIM;
    size_t base = (size_t)bs * DIM;
    for (int d = threadIdx.x; d < DIM; d += 256) {
        float v = 0.5f * wrow[d] + 0.5f * (Wt[d] * t + bt[d]);
        v = valid ? v : 0.f;
        ushort h = f2bf(v);
        ehi[base + d] = h;
        elo[base + d] = f2bf(v - bf2f(h));
    }
}

// ---------------- bf16 MFMA GEMM ------------------------------------------
// C[M,N] = sum_seg A_seg @ B_seg^T  [+bias][+res][relu]
// A: [M,K] bf16 row-major (lda). B stored TRANSPOSED [N,K] bf16 (ldb).
// TOUT: write output transposed-per-batch: Vt[b][col][s] (b=row>>9, s=row&511).
// 128x128 tile, BK=64, 4 waves, 16x16x32 mfma, chunk-XOR LDS swizzle.
template<int SEGS, bool BIAS, bool RELU, bool RES, bool PAIR, bool TOUT>
__global__ __launch_bounds__(256)
void gemm_bf16(const ushort* __restrict__ A0, const ushort* __restrict__ A1,
               const ushort* __restrict__ B0, const ushort* __restrict__ B1,
               const float* __restrict__ bias,
               const ushort* __restrict__ Rh, const ushort* __restrict__ Rl,
               ushort* __restrict__ Oh, ushort* __restrict__ Ol,
               int Md, int Nd, int Kd, int lda, int ldb)
{
    __shared__ __align__(16) ushort As[128 * 64];
    __shared__ __align__(16) ushort Bs[128 * 64];
    char* AsB = (char*)As;
    char* BsB = (char*)Bs;
    const int tid = threadIdx.x;
    const int w = tid >> 6, l = tid & 63;
    const int wr = w >> 1, wc = w & 1;
    const int l15 = l & 15, lg = l >> 4;
    const int row0 = blockIdx.y * 128;
    const int col0 = blockIdx.x * 128;
    const int srow = l >> 3, slot = l & 7;

    f32x4 acc[4][4];
    #pragma unroll
    for (int m = 0; m < 4; m++)
        #pragma unroll
        for (int n = 0; n < 4; n++)
            acc[m][n] = (f32x4){0.f, 0.f, 0.f, 0.f};

    for (int seg = 0; seg < SEGS; ++seg) {
        const ushort* Ap = (seg == 1) ? A1 : A0;
        const ushort* Bp = (seg == 2) ? B1 : B0;
        for (int kt = 0; kt < Kd; kt += 64) {
            __syncthreads();
            #pragma unroll
            for (int r = 0; r < 4; ++r) {
                int row = w * 32 + r * 8 + srow;
                uint4 va = *reinterpret_cast<const uint4*>(
                    Ap + (size_t)(row0 + row) * lda + kt + slot * 8);
                uint4 vb = *reinterpret_cast<const uint4*>(
                    Bp + (size_t)(col0 + row) * ldb + kt + slot * 8);
                int ds = ((slot ^ (row & 7)) << 4) + row * 128;
                *reinterpret_cast<uint4*>(AsB + ds) = va;
                *reinterpret_cast<uint4*>(BsB + ds) = vb;
            }
            __syncthreads();
            #pragma unroll
            for (int ks = 0; ks < 2; ++ks) {
                const int g = ks * 4 + lg;
                short8 af[4], bfr[4];
                #pragma unroll
                for (int m = 0; m < 4; ++m) {
                    int row = wr * 64 + m * 16 + l15;
                    af[m] = *reinterpret_cast<const short8*>(
                        AsB + row * 128 + ((g ^ (row & 7)) << 4));
                }
                #pragma unroll
                for (int n = 0; n < 4; ++n) {
                    int row = wc * 64 + n * 16 + l15;
                    bfr[n] = *reinterpret_cast<const short8*>(
                        BsB + row * 128 + ((g ^ (row & 7)) << 4));
                }
                #pragma unroll
                for (int m = 0; m < 4; ++m)
                    #pragma unroll
                    for (int n = 0; n < 4; ++n)
                        acc[m][n] = __builtin_amdgcn_mfma_f32_16x16x32_bf16(
                            af[m], bfr[n], acc[m][n], 0, 0, 0);
            }
        }
    }

    #pragma unroll
    for (int m = 0; m < 4; ++m) {
        #pragma unroll
        for (int n = 0; n < 4; ++n) {
            int col = col0 + wc * 64 + n * 16 + l15;
            if (TOUT) {
                // transposed-per-batch write: 4 consecutive s per lane -> 8B
                union { uint2 u; ushort s4[4]; } pk;
                #pragma unroll
                for (int j = 0; j < 4; ++j) pk.s4[j] = f2bf(acc[m][n][j]);
                int brow = row0 + wr * 64 + m * 16 + lg * 4;
                size_t idx = ((size_t)(brow >> 9) << 18) + (size_t)col * SEQ + (brow & 511);
                *reinterpret_cast<uint2*>(Oh + idx) = pk.u;
            } else {
                float bia = 0.f;
                if (BIAS) bia = bias[col];
                #pragma unroll
                for (int j = 0; j < 4; ++j) {
                    int row = row0 + wr * 64 + m * 16 + lg * 4 + j;
                    size_t idx = (size_t)row * Nd + col;
                    float v = acc[m][n][j] + bia;
                    if (RES)  v += bf2f(Rh[idx]) + bf2f(Rl[idx]);
                    if (RELU) v = fmaxf(v, 0.f);
                    ushort hv = f2bf(v);
                    Oh[idx] = hv;
                    if (PAIR) Ol[idx] = f2bf(v - bf2f(hv));
                }
            }
        }
    }
}

// ---------------- MFMA flash attention ------------------------------------
// grid (8 qtiles, NHEAD, BATCH); 256 threads = 4 waves; wave owns 16 q-rows.
// Q,K bf16 [b*S+s][512] (head slice); V pre-transposed Vt[b][dh 512][s 512].
// QK^T: mfma(A=Q, B=K). Online softmax in registers (C-layout: lane holds
// rows lg*4+j at col l15; shfl_xor{1,2,4,8} reduces over kv cols).
// P -> per-wave swizzled LDS tile -> A-operand of PV; B = Vt (linear b128).
// O (bf16) overwrites Q in place (disjoint row x col slices per block).
__global__ __launch_bounds__(256)
void attn_mfma(ushort* __restrict__ QO, const ushort* __restrict__ K,
               const ushort* __restrict__ Vt, const float* __restrict__ maskA)
{
    __shared__ __align__(16) ushort Qs[64 * 64];
    __shared__ __align__(16) ushort Ks[64 * 64];
    __shared__ __align__(16) ushort Vs[64 * 64];
    __shared__ __align__(16) ushort Pl[4][16 * 64];
    __shared__ float ms[64];
    const int qt  = blockIdx.x;
    const int h   = blockIdx.y;
    const int b   = blockIdx.z;
    const int tid = threadIdx.x;
    const int w = tid >> 6, l = tid & 63;
    const int l15 = l & 15, lg = l >> 4, l7 = l & 7;
    const int qbase = qt * 64;

    // stage Q tile [64 q][64 dh], chunk-XOR swizzled
    {
        int r = tid >> 3, cl = tid & 7;
        #pragma unroll
        for (int rr = 0; rr < 2; ++rr) {
            int q = r + rr * 32;
            int cg = cl ^ (q & 7);
            uint4 v = *reinterpret_cast<const uint4*>(
                QO + ((size_t)(b * SEQ + qbase + q)) * DIM + h * DHEAD + cg * 8);
            *reinterpret_cast<uint4*>(&Qs[q * 64 + cl * 8]) = v;
        }
    }
    __syncthreads();

    // hoist Q A-frags (2 k-steps of 32 over DH=64)
    short8 af[2];
    #pragma unroll
    for (int s = 0; s < 2; ++s) {
        int q = w * 16 + l15;
        int c = (s * 4 + lg) ^ l7;
        af[s] = *reinterpret_cast<const short8*>(&Qs[q * 64 + c * 8]);
    }

    f32x4 oacc[4];
    #pragma unroll
    for (int t = 0; t < 4; ++t) oacc[t] = (f32x4){0.f, 0.f, 0.f, 0.f};
    float mrun[4], lrun[4];
    #pragma unroll
    for (int j = 0; j < 4; ++j) { mrun[j] = -INFINITY; lrun[j] = 0.f; }

    ushort* pw = Pl[w];

    for (int kv0 = 0; kv0 < SEQ; kv0 += 64) {
        __syncthreads();
        // stage K tile [64 kv][64 dh] and Vt tile [64 dh][64 s], swizzled
        {
            int r = tid >> 3, cl = tid & 7;
            #pragma unroll
            for (int rr = 0; rr < 2; ++rr) {
                int row = r + rr * 32;
                int cg = cl ^ (row & 7);
                uint4 kvv = *reinterpret_cast<const uint4*>(
                    K + ((size_t)(b * SEQ + kv0 + row)) * DIM + h * DHEAD + cg * 8);
                *reinterpret_cast<uint4*>(&Ks[row * 64 + cl * 8]) = kvv;
                uint4 vvv = *reinterpret_cast<const uint4*>(
                    Vt + ((size_t)b << 18) + (size_t)(h * DHEAD + row) * SEQ + kv0 + cg * 8);
                *reinterpret_cast<uint4*>(&Vs[row * 64 + cl * 8]) = vvv;
            }
        }
        if (tid < 64) ms[tid] = maskA[b * SEQ + kv0 + tid];
        __syncthreads();

        // QK^T: 4 kv-tiles x 2 k-steps
        f32x4 sacc[4];
        #pragma unroll
        for (int t = 0; t < 4; ++t) sacc[t] = (f32x4){0.f, 0.f, 0.f, 0.f};
        #pragma unroll
        for (int s = 0; s < 2; ++s) {
            int c = (s * 4 + lg) ^ l7;
            #pragma unroll
            for (int t = 0; t < 4; ++t) {
                int kv = t * 16 + l15;
                short8 bf = *reinterpret_cast<const short8*>(&Ks[kv * 64 + c * 8]);
                sacc[t] = __builtin_amdgcn_mfma_f32_16x16x32_bf16(af[s], bf, sacc[t], 0, 0, 0);
            }
        }

        // mask + scale (mask col = kv0 + t*16 + l15, same for all j)
        float mk[4];
        #pragma unroll
        for (int t = 0; t < 4; ++t) mk[t] = ms[t * 16 + l15];
        #pragma unroll
        for (int t = 0; t < 4; ++t)
            #pragma unroll
            for (int j = 0; j < 4; ++j)
                sacc[t][j] = (mk[t] != 0.f) ? sacc[t][j] * 0.125f : -1e9f;

        // online softmax, rows q = w*16 + lg*4 + j
        float scl[4];
        #pragma unroll
        for (int j = 0; j < 4; ++j) {
            float tm = fmaxf(fmaxf(sacc[0][j], sacc[1][j]),
                             fmaxf(sacc[2][j], sacc[3][j]));
            tm = fmaxf(tm, __shfl_xor(tm, 1));
            tm = fmaxf(tm, __shfl_xor(tm, 2));
            tm = fmaxf(tm, __shfl_xor(tm, 4));
            tm = fmaxf(tm, __shfl_xor(tm, 8));
            float mn = fmaxf(mrun[j], tm);
            scl[j] = __expf(mrun[j] - mn);
            mrun[j] = mn;
        }
        #pragma unroll
        for (int t = 0; t < 4; ++t)
            #pragma unroll
            for (int j = 0; j < 4; ++j)
                sacc[t][j] = __expf(sacc[t][j] - mrun[j]);
        #pragma unroll
        for (int j = 0; j < 4; ++j) {
            float ps = ((sacc[0][j] + sacc[1][j]) + (sacc[2][j] + sacc[3][j]));
            ps += __shfl_xor(ps, 1);
            ps += __shfl_xor(ps, 2);
            ps += __shfl_xor(ps, 4);
            ps += __shfl_xor(ps, 8);
            lrun[j] = lrun[j] * scl[j] + ps;
        }
        #pragma unroll
        for (int t = 0; t < 4; ++t)
            #pragma unroll
            for (int j = 0; j < 4; ++j)
                oacc[t][j] *= scl[j];

        // P (bf16) -> per-wave LDS [16 q][64 kv], chunk-XOR swizzle on kv
        #pragma unroll
        for (int t = 0; t < 4; ++t) {
            #pragma unroll
            for (int j = 0; j < 4; ++j) {
                int qrow = lg * 4 + j;
                int kv = t * 16 + l15;
                int phys = qrow * 64 + (kv & 7) + ((((kv >> 3) ^ (qrow & 7))) << 3);
                pw[phys] = f2bf(sacc[t][j]);
            }
        }
        // same-wave write->read dependency; compiler inserts lgkmcnt waits

        // PV: A = P[16 q][64 kv], B = Vt[dh][kv]; 2 k-steps x 4 dh-tiles
        #pragma unroll
        for (int s = 0; s < 2; ++s) {
            int c = (s * 4 + lg) ^ l7;
            short8 pa = *reinterpret_cast<const short8*>(&pw[l15 * 64 + c * 8]);
            #pragma unroll
            for (int t = 0; t < 4; ++t) {
                int dh = t * 16 + l15;
                short8 vb = *reinterpret_cast<const short8*>(&Vs[dh * 64 + c * 8]);
                oacc[t] = __builtin_amdgcn_mfma_f32_16x16x32_bf16(pa, vb, oacc[t], 0, 0, 0);
            }
        }
    }

    // epilogue: O[q][h*64+dh] = oacc / lrun, in place over Q
    float inv[4];
    #pragma unroll
    for (int j = 0; j < 4; ++j) inv[j] = 1.0f / lrun[j];
    #pragma unroll
    for (int t = 0; t < 4; ++t) {
        #pragma unroll
        for (int j = 0; j < 4; ++j) {
            size_t g = ((size_t)(b * SEQ + qbase + w * 16 + lg * 4 + j)) * DIM
                     + h * DHEAD + t * 16 + l15;
            QO[g] = f2bf(oacc[t][j] * inv[j]);
        }
    }
}

// ---------------- masked mean pool (reads bf16 hi/lo h) --------------------
__global__ __launch_bounds__(512)
void pool_kernel(const ushort* __restrict__ hh, const ushort* __restrict__ hl,
                 const float* __restrict__ maskA, float* __restrict__ pooled)
{
    int b = blockIdx.x;
    int d = threadIdx.x;
    float acc = 0.f, cnt = 0.f;
    for (int s = 0; s < SEQ; s++) {
        float mv = maskA[b * SEQ + s];
        size_t idx = ((size_t)(b * SEQ + s)) * DIM + d;
        acc += mv * (bf2f(hh[idx]) + bf2f(hl[idx]));
        cnt += mv;
    }
    pooled[b * DIM + d] = acc / fmaxf(cnt, 1.f);
}

// ---------------- pooled @ Wp + bp -> henc rows [hoff, hoff+32) ------------
__global__ __launch_bounds__(512)
void proj_kernel(const float* __restrict__ pooled, const float* __restrict__ Wp,
                 const float* __restrict__ bp, float* __restrict__ henc, int hoff)
{
    int b = blockIdx.x;
    int j = threadIdx.x;
    __shared__ float p[DIM];
    p[j] = pooled[b * DIM + j];
    __syncthreads();
    float a0 = 0.f, a1 = 0.f, a2 = 0.f, a3 = 0.f;
    for (int d = 0; d < DIM; d += 4) {
        a0 += p[d]     * Wp[(size_t)d       * DIM + j];
        a1 += p[d + 1] * Wp[(size_t)(d + 1) * DIM + j];
        a2 += p[d + 2] * Wp[(size_t)(d + 2) * DIM + j];
        a3 += p[d + 3] * Wp[(size_t)(d + 3) * DIM + j];
    }
    henc[(size_t)(hoff + b) * DIM + j] = ((a0 + a1) + (a2 + a3)) + bp[j];
}

// ---------------- logits = concat(hH,hF) @ W_out + b_out -------------------
__global__ __launch_bounds__(256)
void logits_kernel(const float* __restrict__ henc, const float* __restrict__ Wout,
                   const float* __restrict__ bout, float* __restrict__ logits)
{
    int b = blockIdx.y;
    int m = blockIdx.x * 256 + threadIdx.x;
    __shared__ float hh[2 * DIM];
    for (int j = threadIdx.x; j < DIM; j += 256) {
        hh[j]       = henc[(size_t)b * DIM + j];
        hh[DIM + j] = henc[(size_t)(BATCH + b) * DIM + j];
    }
    __syncthreads();
    if (m < MM) {
        float a0 = 0.f, a1 = 0.f, a2 = 0.f, a3 = 0.f;
        for (int j = 0; j < 2 * DIM; j += 4) {
            a0 += hh[j]     * Wout[(size_t)j       * MM + m];
            a1 += hh[j + 1] * Wout[(size_t)(j + 1) * MM + m];
            a2 += hh[j + 2] * Wout[(size_t)(j + 2) * MM + m];
            a3 += hh[j + 3] * Wout[(size_t)(j + 3) * MM + m];
        }
        logits[b * MM + m] = ((a0 + a1) + (a2 + a3)) + bout[m];
    }
}

// ---------------- softmax + argmax ----------------
__global__ __launch_bounds__(256)
void smax_kernel(const float* __restrict__ logits, float* __restrict__ out)
{
    int b   = blockIdx.x;
    int tid = threadIdx.x;
    __shared__ float red[256];
    __shared__ int   redi[256];

    float v[4];
    float mx = -INFINITY;
    #pragma unroll
    for (int i = 0; i < 4; i++) {
        int m = tid + i * 256;
        if (m < MM) { v[i] = logits[b * MM + m]; mx = fmaxf(mx, v[i]); }
        else v[i] = -INFINITY;
    }
    red[tid] = mx; __syncthreads();
    for (int st = 128; st > 0; st >>= 1) {
        if (tid < st) red[tid] = fmaxf(red[tid], red[tid + st]);
        __syncthreads();
    }
    mx = red[0]; __syncthreads();

    float sum = 0.f;
    #pragma unroll
    for (int i = 0; i < 4; i++) {
        int m = tid + i * 256;
        if (m < MM) { v[i] = expf(v[i] - mx); sum += v[i]; }
    }
    red[tid] = sum; __syncthreads();
    for (int st = 128; st > 0; st >>= 1) {
        if (tid < st) red[tid] += red[tid + st];
        __syncthreads();
    }
    float inv = 1.0f / red[0]; __syncthreads();

    float bestv = -INFINITY; int besti = 0x7fffffff;
    #pragma unroll
    for (int i = 0; i < 4; i++) {
        int m = tid + i * 256;
        if (m < MM) {
            float lam = v[i] * inv;
            out[b * MM + m] = lam;
            if (lam > bestv) { bestv = lam; besti = m; }
        }
    }
    red[tid] = bestv; redi[tid] = besti; __syncthreads();
    for (int st = 128; st > 0; st >>= 1) {
        if (tid < st) {
            float ov = red[tid + st]; int oi = redi[tid + st];
            if (ov > red[tid] || (ov == red[tid] && oi < redi[tid])) {
                red[tid] = ov; redi[tid] = oi;
            }
        }
        __syncthreads();
    }
    if (tid == 0) out[BATCH * MM + b] = (float)redi[0];
}

// ---------------------------------------------------------------------------
extern "C" void kernel_launch(void* const* d_in, const int* in_sizes, int n_in,
                              void* d_out, int out_size, void* d_ws, size_t ws_size,
                              hipStream_t stream)
{
    const float* xH   = (const float*)d_in[0];
    const float* xF   = (const float*)d_in[1];
    const float* Wm   = (const float*)d_in[2];
    const float* Wt   = (const float*)d_in[3];
    const float* bt   = (const float*)d_in[4];
    const float* Wq   = (const float*)d_in[5];
    const float* Wk   = (const float*)d_in[6];
    const float* Wv   = (const float*)d_in[7];
    const float* Wo   = (const float*)d_in[8];
    const float* W1   = (const float*)d_in[9];
    const float* b1   = (const float*)d_in[10];
    const float* W2   = (const float*)d_in[11];
    const float* b2   = (const float*)d_in[12];
    const float* Wp   = (const float*)d_in[13];
    const float* bp   = (const float*)d_in[14];
    const float* Wout = (const float*)d_in[15];
    const float* bout = (const float*)d_in[16];
    float* out = (float*)d_out;

    float* ws     = (float*)d_ws;
    float*  WmT    = ws + OFF_WMT;
    float*  maskA  = ws + OFF_MASK;
    float*  pooled = ws + OFF_POOL;
    float*  henc   = ws + OFF_HENC;
    float*  logits = ws + OFF_LOG;
    ushort* WqTh   = (ushort*)(ws + OFF_WQTH);
    ushort* WkTh   = (ushort*)(ws + OFF_WKTH);
    ushort* WvTh   = (ushort*)(ws + OFF_WVTH);
    ushort* WoTh   = (ushort*)(ws + OFF_WOTH);
    ushort* W1Th   = (ushort*)(ws + OFF_W1TH);
    ushort* W1Tl   = (ushort*)(ws + OFF_W1TL);
    ushort* W2Th   = (ushort*)(ws + OFF_W2TH);
    ushort* W2Tl   = (ushort*)(ws + OFF_W2TL);
    ushort* ehi    = (ushort*)(ws + OFF_EHI);
    ushort* elo    = (ushort*)(ws + OFF_ELO);
    ushort* Qb     = (ushort*)(ws + OFF_QB);   // Q -> O -> h'_hi
    ushort* Kb     = (ushort*)(ws + OFF_KB);   // K -> h'_lo
    ushort* Vtb    = (ushort*)(ws + OFF_VB);   // V^T per batch
    ushort* rhi    = (ushort*)(ws + OFF_RHI);
    ushort* rlo    = (ushort*)(ws + OFF_RLO);

    // ---- setup (shared by both passes) ----
    transpose_wm<<<dim3(32, 16), 256, 0, stream>>>(Wm, WmT);
    split_wT<false><<<dim3(16, 16), 256, 0, stream>>>(Wq, WqTh, nullptr, DIM, DIM);
    split_wT<false><<<dim3(16, 16), 256, 0, stream>>>(Wk, WkTh, nullptr, DIM, DIM);
    split_wT<false><<<dim3(16, 16), 256, 0, stream>>>(Wv, WvTh, nullptr, DIM, DIM);
    split_wT<false><<<dim3(16, 16), 256, 0, stream>>>(Wo, WoTh, nullptr, DIM, DIM);
    split_wT<true ><<<dim3(64, 16), 256, 0, stream>>>(W1, W1Th, W1Tl, DIM, DFFN);
    split_wT<true ><<<dim3(16, 64), 256, 0, stream>>>(W2, W2Th, W2Tl, DFFN, DIM);

    for (int p = 0; p < 2; p++) {
        const float* x = (p == 0) ? xH : xF;
        // embedding -> e hi/lo + mask
        embed_kernel<<<dim3(ROWS), 256, 0, stream>>>(x, WmT, Wt, bt, ehi, elo, maskA);
        // Q,K = e_hi @ W{q,k}; V = e_hi @ Wv written TRANSPOSED per batch
        gemm_bf16<1,false,false,false,false,false><<<dim3(4, 128), 256, 0, stream>>>(
            ehi, nullptr, WqTh, nullptr, nullptr, nullptr, nullptr,
            Qb, nullptr, ROWS, DIM, DIM, DIM, DIM);
        gemm_bf16<1,false,false,false,false,false><<<dim3(4, 128), 256, 0, stream>>>(
            ehi, nullptr, WkTh, nullptr, nullptr, nullptr, nullptr,
            Kb, nullptr, ROWS, DIM, DIM, DIM, DIM);
        gemm_bf16<1,false,false,false,false,true><<<dim3(4, 128), 256, 0, stream>>>(
            ehi, nullptr, WvTh, nullptr, nullptr, nullptr, nullptr,
            Vtb, nullptr, ROWS, DIM, DIM, DIM, DIM);
        // MFMA attention, O overwrites Q
        attn_mfma<<<dim3(8, NHEAD, BATCH), 256, 0, stream>>>(Qb, Kb, Vtb, maskA);
        // h = e + O @ Wo   (res from e hi/lo, out hi/lo in place over e)
        gemm_bf16<1,false,false,true,true,false><<<dim3(4, 128), 256, 0, stream>>>(
            Qb, nullptr, WoTh, nullptr, nullptr, ehi, elo,
            ehi, elo, ROWS, DIM, DIM, DIM, DIM);
        // FFN over 4 DFF-chunks of 512; split-3 both GEMMs; accumulate into h'
        for (int nc = 0; nc < 4; nc++) {
            gemm_bf16<3,true,true,false,true,false><<<dim3(4, 128), 256, 0, stream>>>(
                ehi, elo, W1Th + (size_t)nc * 512 * DIM, W1Tl + (size_t)nc * 512 * DIM,
                b1 + nc * 512, nullptr, nullptr,
                rhi, rlo, ROWS, 512, DIM, DIM, DIM);
            if (nc == 0)
                gemm_bf16<3,true,false,true,true,false><<<dim3(4, 128), 256, 0, stream>>>(
                    rhi, rlo, W2Th + nc * 512, W2Tl + nc * 512,
                    b2, ehi, elo,
                    Qb, Kb, ROWS, DIM, 512, 512, DFFN);
            else
                gemm_bf16<3,false,false,true,true,false><<<dim3(4, 128), 256, 0, stream>>>(
                    rhi, rlo, W2Th + nc * 512, W2Tl + nc * 512,
                    nullptr, Qb, Kb,
                    Qb, Kb, ROWS, DIM, 512, 512, DFFN);
        }
        // masked mean pool over h' (hi in Qb, lo in Kb)
        pool_kernel<<<dim3(BATCH), 512, 0, stream>>>(Qb, Kb, maskA, pooled);
        // pooled @ Wp + bp
        proj_kernel<<<dim3(BATCH), 512, 0, stream>>>(pooled, Wp, bp, henc, p * BATCH);
    }

    // head
    logits_kernel<<<dim3(4, BATCH), 256, 0, stream>>>(henc, Wout, bout, logits);
    smax_kernel<<<dim3(BATCH), 256, 0, stream>>>(logits, out);
}

// Round 6
// 1013.182 us; speedup vs baseline: 4.4711x; 1.0804x over previous
//
#include <hip/hip_runtime.h>
#include <math.h>

// Problem constants
#define BATCH 32     // per-pass batch (H pass then F pass)
#define SEQ  512
#define DIM  512
#define MM   1000
#define NHEAD 8
#define DHEAD 64
#define DFFN 2048
#define ROWS (BATCH * SEQ)   // 16384 rows per pass

typedef __attribute__((ext_vector_type(8))) short short8;
typedef __attribute__((ext_vector_type(4))) float f32x4;

__device__ __forceinline__ ushort f2bf(float x) {
    unsigned u = __builtin_bit_cast(unsigned, x);
    unsigned r = (u + 0x7FFFu + ((u >> 16) & 1u)) >> 16;
    return (ushort)r;
}
__device__ __forceinline__ float bf2f(ushort h) {
    unsigned u = ((unsigned)h) << 16;
    return __builtin_bit_cast(float, u);
}

// async global->LDS, 16B per lane. LDS dest must be wave-uniform base
// (HW adds lane*16); global src is per-lane. [m97/m104 semantics]
#define GL2LDS(g, s) __builtin_amdgcn_global_load_lds( \
    (const __attribute__((address_space(1))) unsigned int*)(g), \
    (__attribute__((address_space(3))) unsigned int*)(s), 16, 0, 0)

// ---------------------------------------------------------------------------
// ws layout (float32-slot offsets) — total 32,636,928 slots = 130.5 MB
// ---------------------------------------------------------------------------
constexpr size_t OFF_WMT  = 0;         // fp32 [1000][512]
constexpr size_t OFF_MASK = 524288;    // fp32 [16384]
constexpr size_t OFF_POOL = 540672;    // fp32 [32][512]
constexpr size_t OFF_HENC = 557056;    // fp32 [64][512]
constexpr size_t OFF_LOG  = 589824;    // fp32 [32][1000]
constexpr size_t OFF_WQTH = 655360;    // bf16 [512][512]   (each 131072 slots)
constexpr size_t OFF_WKTH = 786432;
constexpr size_t OFF_WVTH = 917504;
constexpr size_t OFF_WOTH = 1048576;
constexpr size_t OFF_W1TH = 1179648;   // bf16 [2048][512]  (524288 slots)
constexpr size_t OFF_W1TL = 1703936;
constexpr size_t OFF_W2TH = 2228224;   // bf16 [512][2048]
constexpr size_t OFF_W2TL = 2752512;
constexpr size_t OFF_EHI  = 3276800;   // bf16 [16384][512] (4194304 slots)
constexpr size_t OFF_ELO  = 7471104;
constexpr size_t OFF_QB   = 11665408;  // bf16 Q -> O -> h'_hi
constexpr size_t OFF_KB   = 15859712;  // bf16 K -> h'_lo
constexpr size_t OFF_VB   = 20054016;  // bf16 V^T per batch [b][512 dh][512 s]
constexpr size_t OFF_RHI  = 24248320;  // bf16 [16384][512] FFN chunk
constexpr size_t OFF_RLO  = 28442624;

// ---------------- transpose W_m [512,1000] -> WmT [1000,512] (fp32) --------
__global__ __launch_bounds__(256)
void transpose_wm(const float* __restrict__ Wm, float* __restrict__ WmT)
{
    __shared__ float tile[32][33];
    int tx = threadIdx.x & 31;
    int ty = threadIdx.x >> 5;
    int mx = blockIdx.x * 32;
    int dy = blockIdx.y * 32;
    for (int i = ty; i < 32; i += 8) {
        int d = dy + i, m = mx + tx;
        tile[i][tx] = (m < MM) ? Wm[(size_t)d * MM + m] : 0.f;
    }
    __syncthreads();
    for (int i = ty; i < 32; i += 8) {
        int m = mx + i, d = dy + tx;
        if (m < MM) WmT[(size_t)m * DIM + d] = tile[tx][i];
    }
}

// ---------------- split+transpose weight: W[K,N] -> WT_h/WT_l [N,K] bf16 ---
template<bool LO>
__global__ __launch_bounds__(256)
void split_wT(const float* __restrict__ W, ushort* __restrict__ Th,
              ushort* __restrict__ Tl, int K, int N)
{
    __shared__ float tile[32][33];
    int tx = threadIdx.x & 31;
    int ty = threadIdx.x >> 5;
    int n0 = blockIdx.x * 32;
    int k0 = blockIdx.y * 32;
    for (int i = ty; i < 32; i += 8)
        tile[i][tx] = W[(size_t)(k0 + i) * N + n0 + tx];
    __syncthreads();
    for (int i = ty; i < 32; i += 8) {
        int n = n0 + i, k = k0 + tx;
        float x = tile[tx][i];
        ushort h = f2bf(x);
        Th[(size_t)n * K + k] = h;
        if (LO) Tl[(size_t)n * K + k] = f2bf(x - bf2f(h));
    }
}

// ---------------- embedding + mask -> e_hi/e_lo bf16 ----------------------
__global__ __launch_bounds__(256)
void embed_kernel(const float* __restrict__ x,
                  const float* __restrict__ WmT, const float* __restrict__ Wt,
                  const float* __restrict__ bt,
                  ushort* __restrict__ ehi, ushort* __restrict__ elo,
                  float* __restrict__ maskA)
{
    int bs = blockIdx.x;
    const float* xp = x + (size_t)bs * 2;
    float t   = xp[0];
    float mkf = xp[1];
    int   mk  = (int)fminf(fmaxf(mkf, 0.f), (float)(MM - 1));
    bool  valid = (t >= 0.f);
    if (threadIdx.x == 0) maskA[bs] = valid ? 1.f : 0.f;
    const float* wrow = WmT + (size_t)mk * DIM;
    size_t base = (size_t)bs * DIM;
    for (int d = threadIdx.x; d < DIM; d += 256) {
        float v = 0.5f * wrow[d] + 0.5f * (Wt[d] * t + bt[d]);
        v = valid ? v : 0.f;
        ushort h = f2bf(v);
        ehi[base + d] = h;
        elo[base + d] = f2bf(v - bf2f(h));
    }
}

// ---------------- bf16 MFMA GEMM ------------------------------------------
// C[M,N] = sum_seg A_seg @ B_seg^T  [+bias][+res][relu]
// A: [M,K] bf16 row-major (lda). B stored TRANSPOSED [N,K] bf16 (ldb).
// TOUT: write output transposed-per-batch: Vt[b][col][s] (b=row>>9, s=row&511).
// 128x128 tile, BK=64, 4 waves, 16x16x32 mfma.
// Staging: global_load_lds width=16, LINEAR LDS dest (wave base + lane*16),
// XOR swizzle applied to the per-lane GLOBAL chunk select; frag reads apply
// the same XOR (rule-21 both-sides involution). Conflict-free.
template<int SEGS, bool BIAS, bool RELU, bool RES, bool PAIR, bool TOUT>
__global__ __launch_bounds__(256)
void gemm_bf16(const ushort* __restrict__ A0, const ushort* __restrict__ A1,
               const ushort* __restrict__ B0, const ushort* __restrict__ B1,
               const float* __restrict__ bias,
               const ushort* __restrict__ Rh, const ushort* __restrict__ Rl,
               ushort* __restrict__ Oh, ushort* __restrict__ Ol,
               int Md, int Nd, int Kd, int lda, int ldb)
{
    __shared__ __align__(16) ushort As[128 * 64];
    __shared__ __align__(16) ushort Bs[128 * 64];
    char* AsB = (char*)As;
    char* BsB = (char*)Bs;
    const int tid = threadIdx.x;
    const int w = tid >> 6, l = tid & 63;
    const int wr = w >> 1, wc = w & 1;
    const int l15 = l & 15, lg = l >> 4;
    const int row0 = blockIdx.y * 128;
    const int col0 = blockIdx.x * 128;
    const int lrow   = l >> 3;              // 0..7 : row within 8-row stripe
    const int gchunk = (l & 7) ^ lrow;      // pre-swizzled global 16B chunk

    f32x4 acc[4][4];
    #pragma unroll
    for (int m = 0; m < 4; m++)
        #pragma unroll
        for (int n = 0; n < 4; n++)
            acc[m][n] = (f32x4){0.f, 0.f, 0.f, 0.f};

    for (int seg = 0; seg < SEGS; ++seg) {
        const ushort* Ap = (seg == 1) ? A1 : A0;
        const ushort* Bp = (seg == 2) ? B1 : B0;
        for (int kt = 0; kt < Kd; kt += 64) {
            __syncthreads();
            #pragma unroll
            for (int r = 0; r < 4; ++r) {
                int rowb = w * 32 + r * 8;          // wave-uniform stripe base
                int row  = rowb + lrow;
                GL2LDS(Ap + (size_t)(row0 + row) * lda + kt + gchunk * 8,
                       &As[rowb * 64]);
                GL2LDS(Bp + (size_t)(col0 + row) * ldb + kt + gchunk * 8,
                       &Bs[rowb * 64]);
            }
            __syncthreads();
            #pragma unroll
            for (int ks = 0; ks < 2; ++ks) {
                const int g = ks * 4 + lg;
                short8 af[4], bfr[4];
                #pragma unroll
                for (int m = 0; m < 4; ++m) {
                    int row = wr * 64 + m * 16 + l15;
                    af[m] = *reinterpret_cast<const short8*>(
                        AsB + row * 128 + ((g ^ (row & 7)) << 4));
                }
                #pragma unroll
                for (int n = 0; n < 4; ++n) {
                    int row = wc * 64 + n * 16 + l15;
                    bfr[n] = *reinterpret_cast<const short8*>(
                        BsB + row * 128 + ((g ^ (row & 7)) << 4));
                }
                #pragma unroll
                for (int m = 0; m < 4; ++m)
                    #pragma unroll
                    for (int n = 0; n < 4; ++n)
                        acc[m][n] = __builtin_amdgcn_mfma_f32_16x16x32_bf16(
                            af[m], bfr[n], acc[m][n], 0, 0, 0);
            }
        }
    }

    #pragma unroll
    for (int m = 0; m < 4; ++m) {
        #pragma unroll
        for (int n = 0; n < 4; ++n) {
            int col = col0 + wc * 64 + n * 16 + l15;
            if (TOUT) {
                union { uint2 u; ushort s4[4]; } pk;
                #pragma unroll
                for (int j = 0; j < 4; ++j) pk.s4[j] = f2bf(acc[m][n][j]);
                int brow = row0 + wr * 64 + m * 16 + lg * 4;
                size_t idx = ((size_t)(brow >> 9) << 18) + (size_t)col * SEQ + (brow & 511);
                *reinterpret_cast<uint2*>(Oh + idx) = pk.u;
            } else {
                float bia = 0.f;
                if (BIAS) bia = bias[col];
                #pragma unroll
                for (int j = 0; j < 4; ++j) {
                    int row = row0 + wr * 64 + m * 16 + lg * 4 + j;
                    size_t idx = (size_t)row * Nd + col;
                    float v = acc[m][n][j] + bia;
                    if (RES)  v += bf2f(Rh[idx]) + bf2f(Rl[idx]);
                    if (RELU) v = fmaxf(v, 0.f);
                    ushort hv = f2bf(v);
                    Oh[idx] = hv;
                    if (PAIR) Ol[idx] = f2bf(v - bf2f(hv));
                }
            }
        }
    }
}

// ---------------- MFMA flash attention ------------------------------------
// grid (NHEAD, BATCH, 8): qt-partners (same h,b K/V slice) are 256 apart in
// dispatch order -> same XCD under %8 round-robin -> L2 reuse of K/V.
// 256 threads = 4 waves; wave owns 16 q-rows. Staging via global_load_lds
// (linear LDS dest, pre-swizzled global chunk). O overwrites Q in place.
__global__ __launch_bounds__(256)
void attn_mfma(ushort* __restrict__ QO, const ushort* __restrict__ K,
               const ushort* __restrict__ Vt, const float* __restrict__ maskA)
{
    __shared__ __align__(16) ushort Qs[64 * 64];
    __shared__ __align__(16) ushort Ks[64 * 64];
    __shared__ __align__(16) ushort Vs[64 * 64];
    __shared__ __align__(16) ushort Pl[4][16 * 64];
    __shared__ float ms[64];
    const int h   = blockIdx.x;
    const int b   = blockIdx.y;
    const int qt  = blockIdx.z;
    const int tid = threadIdx.x;
    const int w = tid >> 6, l = tid & 63;
    const int l15 = l & 15, lg = l >> 4, l7 = l & 7;
    const int lrow   = l >> 3;
    const int gchunk = (l & 7) ^ lrow;
    const int qbase = qt * 64;

    // stage Q tile [64 q][64 dh] via global_load_lds, swizzled source
    #pragma unroll
    for (int rr = 0; rr < 2; ++rr) {
        int rowb = rr * 32 + w * 8;             // wave-uniform
        int q = rowb + lrow;
        GL2LDS(QO + ((size_t)(b * SEQ + qbase + q)) * DIM + h * DHEAD + gchunk * 8,
               &Qs[rowb * 64]);
    }
    __syncthreads();

    // hoist Q A-frags (2 k-steps of 32 over DH=64)
    short8 af[2];
    #pragma unroll
    for (int s = 0; s < 2; ++s) {
        int q = w * 16 + l15;
        int c = (s * 4 + lg) ^ l7;
        af[s] = *reinterpret_cast<const short8*>(&Qs[q * 64 + c * 8]);
    }

    f32x4 oacc[4];
    #pragma unroll
    for (int t = 0; t < 4; ++t) oacc[t] = (f32x4){0.f, 0.f, 0.f, 0.f};
    float mrun[4], lrun[4];
    #pragma unroll
    for (int j = 0; j < 4; ++j) { mrun[j] = -INFINITY; lrun[j] = 0.f; }

    ushort* pw = Pl[w];

    for (int kv0 = 0; kv0 < SEQ; kv0 += 64) {
        __syncthreads();
        #pragma unroll
        for (int rr = 0; rr < 2; ++rr) {
            int rowb = rr * 32 + w * 8;
            int row = rowb + lrow;
            GL2LDS(K + ((size_t)(b * SEQ + kv0 + row)) * DIM + h * DHEAD + gchunk * 8,
                   &Ks[rowb * 64]);
            GL2LDS(Vt + ((size_t)b << 18) + (size_t)(h * DHEAD + row) * SEQ + kv0 + gchunk * 8,
                   &Vs[rowb * 64]);
        }
        if (tid < 64) ms[tid] = maskA[b * SEQ + kv0 + tid];
        __syncthreads();

        // QK^T: 4 kv-tiles x 2 k-steps
        f32x4 sacc[4];
        #pragma unroll
        for (int t = 0; t < 4; ++t) sacc[t] = (f32x4){0.f, 0.f, 0.f, 0.f};
        #pragma unroll
        for (int s = 0; s < 2; ++s) {
            int c = (s * 4 + lg) ^ l7;
            #pragma unroll
            for (int t = 0; t < 4; ++t) {
                int kv = t * 16 + l15;
                short8 bf = *reinterpret_cast<const short8*>(&Ks[kv * 64 + c * 8]);
                sacc[t] = __builtin_amdgcn_mfma_f32_16x16x32_bf16(af[s], bf, sacc[t], 0, 0, 0);
            }
        }

        float mk[4];
        #pragma unroll
        for (int t = 0; t < 4; ++t) mk[t] = ms[t * 16 + l15];
        #pragma unroll
        for (int t = 0; t < 4; ++t)
            #pragma unroll
            for (int j = 0; j < 4; ++j)
                sacc[t][j] = (mk[t] != 0.f) ? sacc[t][j] * 0.125f : -1e9f;

        // online softmax, rows q = w*16 + lg*4 + j
        float scl[4];
        #pragma unroll
        for (int j = 0; j < 4; ++j) {
            float tm = fmaxf(fmaxf(sacc[0][j], sacc[1][j]),
                             fmaxf(sacc[2][j], sacc[3][j]));
            tm = fmaxf(tm, __shfl_xor(tm, 1));
            tm = fmaxf(tm, __shfl_xor(tm, 2));
            tm = fmaxf(tm, __shfl_xor(tm, 4));
            tm = fmaxf(tm, __shfl_xor(tm, 8));
            float mn = fmaxf(mrun[j], tm);
            scl[j] = __expf(mrun[j] - mn);
            mrun[j] = mn;
        }
        #pragma unroll
        for (int t = 0; t < 4; ++t)
            #pragma unroll
            for (int j = 0; j < 4; ++j)
                sacc[t][j] = __expf(sacc[t][j] - mrun[j]);
        #pragma unroll
        for (int j = 0; j < 4; ++j) {
            float ps = ((sacc[0][j] + sacc[1][j]) + (sacc[2][j] + sacc[3][j]));
            ps += __shfl_xor(ps, 1);
            ps += __shfl_xor(ps, 2);
            ps += __shfl_xor(ps, 4);
            ps += __shfl_xor(ps, 8);
            lrun[j] = lrun[j] * scl[j] + ps;
        }
        #pragma unroll
        for (int t = 0; t < 4; ++t)
            #pragma unroll
            for (int j = 0; j < 4; ++j)
                oacc[t][j] *= scl[j];

        // P (bf16) -> per-wave LDS [16 q][64 kv], chunk-XOR swizzle on kv
        #pragma unroll
        for (int t = 0; t < 4; ++t) {
            #pragma unroll
            for (int j = 0; j < 4; ++j) {
                int qrow = lg * 4 + j;
                int kv = t * 16 + l15;
                int phys = qrow * 64 + (kv & 7) + ((((kv >> 3) ^ (qrow & 7))) << 3);
                pw[phys] = f2bf(sacc[t][j]);
            }
        }

        // PV: A = P[16 q][64 kv], B = Vt[dh][kv]; 2 k-steps x 4 dh-tiles
        #pragma unroll
        for (int s = 0; s < 2; ++s) {
            int c = (s * 4 + lg) ^ l7;
            short8 pa = *reinterpret_cast<const short8*>(&pw[l15 * 64 + c * 8]);
            #pragma unroll
            for (int t = 0; t < 4; ++t) {
                int dh = t * 16 + l15;
                short8 vb = *reinterpret_cast<const short8*>(&Vs[dh * 64 + c * 8]);
                oacc[t] = __builtin_amdgcn_mfma_f32_16x16x32_bf16(pa, vb, oacc[t], 0, 0, 0);
            }
        }
    }

    // epilogue: O[q][h*64+dh] = oacc / lrun, in place over Q
    float inv[4];
    #pragma unroll
    for (int j = 0; j < 4; ++j) inv[j] = 1.0f / lrun[j];
    #pragma unroll
    for (int t = 0; t < 4; ++t) {
        #pragma unroll
        for (int j = 0; j < 4; ++j) {
            size_t g = ((size_t)(b * SEQ + qbase + w * 16 + lg * 4 + j)) * DIM
                     + h * DHEAD + t * 16 + l15;
            QO[g] = f2bf(oacc[t][j] * inv[j]);
        }
    }
}

// ---------------- masked mean pool (reads bf16 hi/lo h) --------------------
// grid (BATCH, 4): block handles 128 d-cols; 8-way s-split, uint vec loads.
__global__ __launch_bounds__(512)
void pool_kernel(const ushort* __restrict__ hh, const ushort* __restrict__ hl,
                 const float* __restrict__ maskA, float* __restrict__ pooled)
{
    int b  = blockIdx.x;
    int dq = blockIdx.y;
    int dl = threadIdx.x & 63;       // 64 d-pairs
    int sg = threadIdx.x >> 6;       // 0..7 s-group
    int d  = dq * 128 + dl * 2;
    float a0 = 0.f, a1 = 0.f, cnt = 0.f;
    for (int s = sg; s < SEQ; s += 8) {
        float mv = maskA[b * SEQ + s];
        size_t idx = ((size_t)(b * SEQ + s)) * DIM + d;
        unsigned vh = *reinterpret_cast<const unsigned*>(&hh[idx]);
        unsigned vl = *reinterpret_cast<const unsigned*>(&hl[idx]);
        a0 += mv * (bf2f((ushort)(vh & 0xffff)) + bf2f((ushort)(vl & 0xffff)));
        a1 += mv * (bf2f((ushort)(vh >> 16))    + bf2f((ushort)(vl >> 16)));
        cnt += mv;
    }
    __shared__ float r0[8][64];
    __shared__ float r1[8][64];
    __shared__ float rc[8];
    r0[sg][dl] = a0;
    r1[sg][dl] = a1;
    if (dl == 0) rc[sg] = cnt;
    __syncthreads();
    if (sg == 0) {
        float t0 = 0.f, t1 = 0.f, c = 0.f;
        #pragma unroll
        for (int g = 0; g < 8; ++g) { t0 += r0[g][dl]; t1 += r1[g][dl]; c += rc[g]; }
        float invc = 1.0f / fmaxf(c, 1.f);
        pooled[b * DIM + d]     = t0 * invc;
        pooled[b * DIM + d + 1] = t1 * invc;
    }
}

// ---------------- pooled @ Wp + bp -> henc rows [hoff, hoff+32) ------------
__global__ __launch_bounds__(512)
void proj_kernel(const float* __restrict__ pooled, const float* __restrict__ Wp,
                 const float* __restrict__ bp, float* __restrict__ henc, int hoff)
{
    int b = blockIdx.x;
    int j = threadIdx.x;
    __shared__ float p[DIM];
    p[j] = pooled[b * DIM + j];
    __syncthreads();
    float a0 = 0.f, a1 = 0.f, a2 = 0.f, a3 = 0.f;
    for (int d = 0; d < DIM; d += 4) {
        a0 += p[d]     * Wp[(size_t)d       * DIM + j];
        a1 += p[d + 1] * Wp[(size_t)(d + 1) * DIM + j];
        a2 += p[d + 2] * Wp[(size_t)(d + 2) * DIM + j];
        a3 += p[d + 3] * Wp[(size_t)(d + 3) * DIM + j];
    }
    henc[(size_t)(hoff + b) * DIM + j] = ((a0 + a1) + (a2 + a3)) + bp[j];
}

// ---------------- logits = concat(hH,hF) @ W_out + b_out -------------------
__global__ __launch_bounds__(256)
void logits_kernel(const float* __restrict__ henc, const float* __restrict__ Wout,
                   const float* __restrict__ bout, float* __restrict__ logits)
{
    int b = blockIdx.y;
    int m = blockIdx.x * 256 + threadIdx.x;
    __shared__ float hh[2 * DIM];
    for (int j = threadIdx.x; j < DIM; j += 256) {
        hh[j]       = henc[(size_t)b * DIM + j];
        hh[DIM + j] = henc[(size_t)(BATCH + b) * DIM + j];
    }
    __syncthreads();
    if (m < MM) {
        float a0 = 0.f, a1 = 0.f, a2 = 0.f, a3 = 0.f;
        for (int j = 0; j < 2 * DIM; j += 4) {
            a0 += hh[j]     * Wout[(size_t)j       * MM + m];
            a1 += hh[j + 1] * Wout[(size_t)(j + 1) * MM + m];
            a2 += hh[j + 2] * Wout[(size_t)(j + 2) * MM + m];
            a3 += hh[j + 3] * Wout[(size_t)(j + 3) * MM + m];
        }
        logits[b * MM + m] = ((a0 + a1) + (a2 + a3)) + bout[m];
    }
}

// ---------------- softmax + argmax ----------------
__global__ __launch_bounds__(256)
void smax_kernel(const float* __restrict__ logits, float* __restrict__ out)
{
    int b   = blockIdx.x;
    int tid = threadIdx.x;
    __shared__ float red[256];
    __shared__ int   redi[256];

    float v[4];
    float mx = -INFINITY;
    #pragma unroll
    for (int i = 0; i < 4; i++) {
        int m = tid + i * 256;
        if (m < MM) { v[i] = logits[b * MM + m]; mx = fmaxf(mx, v[i]); }
        else v[i] = -INFINITY;
    }
    red[tid] = mx; __syncthreads();
    for (int st = 128; st > 0; st >>= 1) {
        if (tid < st) red[tid] = fmaxf(red[tid], red[tid + st]);
        __syncthreads();
    }
    mx = red[0]; __syncthreads();

    float sum = 0.f;
    #pragma unroll
    for (int i = 0; i < 4; i++) {
        int m = tid + i * 256;
        if (m < MM) { v[i] = expf(v[i] - mx); sum += v[i]; }
    }
    red[tid] = sum; __syncthreads();
    for (int st = 128; st > 0; st >>= 1) {
        if (tid < st) red[tid] += red[tid + st];
        __syncthreads();
    }
    float inv = 1.0f / red[0]; __syncthreads();

    float bestv = -INFINITY; int besti = 0x7fffffff;
    #pragma unroll
    for (int i = 0; i < 4; i++) {
        int m = tid + i * 256;
        if (m < MM) {
            float lam = v[i] * inv;
            out[b * MM + m] = lam;
            if (lam > bestv) { bestv = lam; besti = m; }
        }
    }
    red[tid] = bestv; redi[tid] = besti; __syncthreads();
    for (int st = 128; st > 0; st >>= 1) {
        if (tid < st) {
            float ov = red[tid + st]; int oi = redi[tid + st];
            if (ov > red[tid] || (ov == red[tid] && oi < redi[tid])) {
                red[tid] = ov; redi[tid] = oi;
            }
        }
        __syncthreads();
    }
    if (tid == 0) out[BATCH * MM + b] = (float)redi[0];
}

// ---------------------------------------------------------------------------
extern "C" void kernel_launch(void* const* d_in, const int* in_sizes, int n_in,
                              void* d_out, int out_size, void* d_ws, size_t ws_size,
                              hipStream_t stream)
{
    const float* xH   = (const float*)d_in[0];
    const float* xF   = (const float*)d_in[1];
    const float* Wm   = (const float*)d_in[2];
    const float* Wt   = (const float*)d_in[3];
    const float* bt   = (const float*)d_in[4];
    const float* Wq   = (const float*)d_in[5];
    const float* Wk   = (const float*)d_in[6];
    const float* Wv   = (const float*)d_in[7];
    const float* Wo   = (const float*)d_in[8];
    const float* W1   = (const float*)d_in[9];
    const float* b1   = (const float*)d_in[10];
    const float* W2   = (const float*)d_in[11];
    const float* b2   = (const float*)d_in[12];
    const float* Wp   = (const float*)d_in[13];
    const float* bp   = (const float*)d_in[14];
    const float* Wout = (const float*)d_in[15];
    const float* bout = (const float*)d_in[16];
    float* out = (float*)d_out;

    float* ws     = (float*)d_ws;
    float*  WmT    = ws + OFF_WMT;
    float*  maskA  = ws + OFF_MASK;
    float*  pooled = ws + OFF_POOL;
    float*  henc   = ws + OFF_HENC;
    float*  logits = ws + OFF_LOG;
    ushort* WqTh   = (ushort*)(ws + OFF_WQTH);
    ushort* WkTh   = (ushort*)(ws + OFF_WKTH);
    ushort* WvTh   = (ushort*)(ws + OFF_WVTH);
    ushort* WoTh   = (ushort*)(ws + OFF_WOTH);
    ushort* W1Th   = (ushort*)(ws + OFF_W1TH);
    ushort* W1Tl   = (ushort*)(ws + OFF_W1TL);
    ushort* W2Th   = (ushort*)(ws + OFF_W2TH);
    ushort* W2Tl   = (ushort*)(ws + OFF_W2TL);
    ushort* ehi    = (ushort*)(ws + OFF_EHI);
    ushort* elo    = (ushort*)(ws + OFF_ELO);
    ushort* Qb     = (ushort*)(ws + OFF_QB);   // Q -> O -> h'_hi
    ushort* Kb     = (ushort*)(ws + OFF_KB);   // K -> h'_lo
    ushort* Vtb    = (ushort*)(ws + OFF_VB);   // V^T per batch
    ushort* rhi    = (ushort*)(ws + OFF_RHI);
    ushort* rlo    = (ushort*)(ws + OFF_RLO);

    // ---- setup (shared by both passes) ----
    transpose_wm<<<dim3(32, 16), 256, 0, stream>>>(Wm, WmT);
    split_wT<false><<<dim3(16, 16), 256, 0, stream>>>(Wq, WqTh, nullptr, DIM, DIM);
    split_wT<false><<<dim3(16, 16), 256, 0, stream>>>(Wk, WkTh, nullptr, DIM, DIM);
    split_wT<false><<<dim3(16, 16), 256, 0, stream>>>(Wv, WvTh, nullptr, DIM, DIM);
    split_wT<false><<<dim3(16, 16), 256, 0, stream>>>(Wo, WoTh, nullptr, DIM, DIM);
    split_wT<true ><<<dim3(64, 16), 256, 0, stream>>>(W1, W1Th, W1Tl, DIM, DFFN);
    split_wT<true ><<<dim3(16, 64), 256, 0, stream>>>(W2, W2Th, W2Tl, DFFN, DIM);

    for (int p = 0; p < 2; p++) {
        const float* x = (p == 0) ? xH : xF;
        // embedding -> e hi/lo + mask
        embed_kernel<<<dim3(ROWS), 256, 0, stream>>>(x, WmT, Wt, bt, ehi, elo, maskA);
        // Q,K = e_hi @ W{q,k}; V = e_hi @ Wv written TRANSPOSED per batch
        gemm_bf16<1,false,false,false,false,false><<<dim3(4, 128), 256, 0, stream>>>(
            ehi, nullptr, WqTh, nullptr, nullptr, nullptr, nullptr,
            Qb, nullptr, ROWS, DIM, DIM, DIM, DIM);
        gemm_bf16<1,false,false,false,false,false><<<dim3(4, 128), 256, 0, stream>>>(
            ehi, nullptr, WkTh, nullptr, nullptr, nullptr, nullptr,
            Kb, nullptr, ROWS, DIM, DIM, DIM, DIM);
        gemm_bf16<1,false,false,false,false,true><<<dim3(4, 128), 256, 0, stream>>>(
            ehi, nullptr, WvTh, nullptr, nullptr, nullptr, nullptr,
            Vtb, nullptr, ROWS, DIM, DIM, DIM, DIM);
        // MFMA attention, O overwrites Q
        attn_mfma<<<dim3(NHEAD, BATCH, 8), 256, 0, stream>>>(Qb, Kb, Vtb, maskA);
        // h = e + O @ Wo   (res from e hi/lo, out hi/lo in place over e)
        gemm_bf16<1,false,false,true,true,false><<<dim3(4, 128), 256, 0, stream>>>(
            Qb, nullptr, WoTh, nullptr, nullptr, ehi, elo,
            ehi, elo, ROWS, DIM, DIM, DIM, DIM);
        // FFN over 4 DFF-chunks of 512; split-3 both GEMMs; accumulate into h'
        for (int nc = 0; nc < 4; nc++) {
            gemm_bf16<3,true,true,false,true,false><<<dim3(4, 128), 256, 0, stream>>>(
                ehi, elo, W1Th + (size_t)nc * 512 * DIM, W1Tl + (size_t)nc * 512 * DIM,
                b1 + nc * 512, nullptr, nullptr,
                rhi, rlo, ROWS, 512, DIM, DIM, DIM);
            if (nc == 0)
                gemm_bf16<3,true,false,true,true,false><<<dim3(4, 128), 256, 0, stream>>>(
                    rhi, rlo, W2Th + nc * 512, W2Tl + nc * 512,
                    b2, ehi, elo,
                    Qb, Kb, ROWS, DIM, 512, 512, DFFN);
            else
                gemm_bf16<3,false,false,true,true,false><<<dim3(4, 128), 256, 0, stream>>>(
                    rhi, rlo, W2Th + nc * 512, W2Tl + nc * 512,
                    nullptr, Qb, Kb,
                    Qb, Kb, ROWS, DIM, 512, 512, DFFN);
        }
        // masked mean pool over h' (hi in Qb, lo in Kb)
        pool_kernel<<<dim3(BATCH, 4), 512, 0, stream>>>(Qb, Kb, maskA, pooled);
        // pooled @ Wp + bp
        proj_kernel<<<dim3(BATCH), 512, 0, stream>>>(pooled, Wp, bp, henc, p * BATCH);
    }

    // head
    logits_kernel<<<dim3(4, BATCH), 256, 0, stream>>>(henc, Wout, bout, logits);
    smax_kernel<<<dim3(BATCH), 256, 0, stream>>>(logits, out);
}

// Round 7
// 988.182 us; speedup vs baseline: 4.5842x; 1.0253x over previous
//
#include <hip/hip_runtime.h>
#include <math.h>

// Problem constants
#define BATCH 32     // per-pass batch (H pass then F pass)
#define SEQ  512
#define DIM  512
#define MM   1000
#define NHEAD 8
#define DHEAD 64
#define DFFN 2048
#define ROWS (BATCH * SEQ)   // 16384 rows per pass

typedef __attribute__((ext_vector_type(8))) short short8;
typedef __attribute__((ext_vector_type(4))) float f32x4;

__device__ __forceinline__ ushort f2bf(float x) {
    unsigned u = __builtin_bit_cast(unsigned, x);
    unsigned r = (u + 0x7FFFu + ((u >> 16) & 1u)) >> 16;
    return (ushort)r;
}
__device__ __forceinline__ float bf2f(ushort h) {
    unsigned u = ((unsigned)h) << 16;
    return __builtin_bit_cast(float, u);
}

// async global->LDS, 16B per lane. LDS dest must be wave-uniform base
// (HW adds lane*16); global src is per-lane. [m97/m104 semantics]
#define GL2LDS(g, s) __builtin_amdgcn_global_load_lds( \
    (const __attribute__((address_space(1))) unsigned int*)(g), \
    (__attribute__((address_space(3))) unsigned int*)(s), 16, 0, 0)

// ---------------------------------------------------------------------------
// ws layout (float32-slot offsets) — total 32,636,928 slots = 130.5 MB
// ---------------------------------------------------------------------------
constexpr size_t OFF_WMT  = 0;         // fp32 [1000][512]
constexpr size_t OFF_MASK = 524288;    // fp32 [16384]
constexpr size_t OFF_POOL = 540672;    // fp32 [32][512]
constexpr size_t OFF_HENC = 557056;    // fp32 [64][512]
constexpr size_t OFF_LOG  = 589824;    // fp32 [32][1000]
constexpr size_t OFF_WQTH = 655360;    // bf16 [512][512]   (each 131072 slots)
constexpr size_t OFF_WKTH = 786432;    //   Wq/Wk/Wv contiguous => [1536][512]
constexpr size_t OFF_WVTH = 917504;
constexpr size_t OFF_WOTH = 1048576;
constexpr size_t OFF_W1TH = 1179648;   // bf16 [2048][512]  (524288 slots)
constexpr size_t OFF_W1TL = 1703936;
constexpr size_t OFF_W2TH = 2228224;   // bf16 [512][2048]
constexpr size_t OFF_W2TL = 2752512;
constexpr size_t OFF_EHI  = 3276800;   // bf16 [16384][512] (4194304 slots)
constexpr size_t OFF_ELO  = 7471104;
constexpr size_t OFF_QB   = 11665408;  // bf16 Q -> O -> h'_hi
constexpr size_t OFF_KB   = 15859712;  // bf16 K -> h'_lo
constexpr size_t OFF_VB   = 20054016;  // bf16 V^T per batch [b][512 dh][512 s]
constexpr size_t OFF_RHI  = 24248320;  // bf16 [16384][512] FFN chunk
constexpr size_t OFF_RLO  = 28442624;

// ---------------- transpose W_m [512,1000] -> WmT [1000,512] (fp32) --------
__global__ __launch_bounds__(256)
void transpose_wm(const float* __restrict__ Wm, float* __restrict__ WmT)
{
    __shared__ float tile[32][33];
    int tx = threadIdx.x & 31;
    int ty = threadIdx.x >> 5;
    int mx = blockIdx.x * 32;
    int dy = blockIdx.y * 32;
    for (int i = ty; i < 32; i += 8) {
        int d = dy + i, m = mx + tx;
        tile[i][tx] = (m < MM) ? Wm[(size_t)d * MM + m] : 0.f;
    }
    __syncthreads();
    for (int i = ty; i < 32; i += 8) {
        int m = mx + i, d = dy + tx;
        if (m < MM) WmT[(size_t)m * DIM + d] = tile[tx][i];
    }
}

// ---------------- split+transpose weight: W[K,N] -> WT_h/WT_l [N,K] bf16 ---
template<bool LO>
__global__ __launch_bounds__(256)
void split_wT(const float* __restrict__ W, ushort* __restrict__ Th,
              ushort* __restrict__ Tl, int K, int N)
{
    __shared__ float tile[32][33];
    int tx = threadIdx.x & 31;
    int ty = threadIdx.x >> 5;
    int n0 = blockIdx.x * 32;
    int k0 = blockIdx.y * 32;
    for (int i = ty; i < 32; i += 8)
        tile[i][tx] = W[(size_t)(k0 + i) * N + n0 + tx];
    __syncthreads();
    for (int i = ty; i < 32; i += 8) {
        int n = n0 + i, k = k0 + tx;
        float x = tile[tx][i];
        ushort h = f2bf(x);
        Th[(size_t)n * K + k] = h;
        if (LO) Tl[(size_t)n * K + k] = f2bf(x - bf2f(h));
    }
}

// ---------------- embedding + mask -> e_hi/e_lo bf16 ----------------------
__global__ __launch_bounds__(256)
void embed_kernel(const float* __restrict__ x,
                  const float* __restrict__ WmT, const float* __restrict__ Wt,
                  const float* __restrict__ bt,
                  ushort* __restrict__ ehi, ushort* __restrict__ elo,
                  float* __restrict__ maskA)
{
    int bs = blockIdx.x;
    const float* xp = x + (size_t)bs * 2;
    float t   = xp[0];
    float mkf = xp[1];
    int   mk  = (int)fminf(fmaxf(mkf, 0.f), (float)(MM - 1));
    bool  valid = (t >= 0.f);
    if (threadIdx.x == 0) maskA[bs] = valid ? 1.f : 0.f;
    const float* wrow = WmT + (size_t)mk * DIM;
    size_t base = (size_t)bs * DIM;
    for (int d = threadIdx.x; d < DIM; d += 256) {
        float v = 0.5f * wrow[d] + 0.5f * (Wt[d] * t + bt[d]);
        v = valid ? v : 0.f;
        ushort h = f2bf(v);
        ehi[base + d] = h;
        elo[base + d] = f2bf(v - bf2f(h));
    }
}

// ---------------- bf16 MFMA GEMM, 2-phase double-buffered ------------------
// C[M,N] = sum_seg A_seg @ B_seg^T  [+bias][+res][relu]
// A: [M,K] bf16 row-major (lda). B stored TRANSPOSED [N,K] bf16 (ldb).
// 128x128 tile, BK=64, 4 waves, 16x16x32 mfma.
// Staging: global_load_lds width=16, linear LDS dest, XOR swizzle folded into
// per-lane GLOBAL chunk select; frag reads apply the same XOR (rule 21).
// Pipeline (T3-minimum): stage(tile0); barrier; loop { stage(next into buf^1);
// compute(buf); barrier }  — prefetch hides load latency under MFMA.
// TRIPLE: B is concat [1536][512] of Wq/Wk/Wv; cols 0-511 -> Oh (Q),
// 512-1023 -> Ol (K), 1024-1535 -> Ot transposed-per-batch (V^T).
// TOUT: whole output written transposed-per-batch (unused when TRIPLE).
template<int SEGS, bool BIAS, bool RELU, bool RES, bool PAIR, bool TOUT, bool TRIPLE>
__global__ __launch_bounds__(256)
void gemm_bf16(const ushort* __restrict__ A0, const ushort* __restrict__ A1,
               const ushort* __restrict__ B0, const ushort* __restrict__ B1,
               const float* __restrict__ bias,
               const ushort* __restrict__ Rh, const ushort* __restrict__ Rl,
               ushort* __restrict__ Oh, ushort* __restrict__ Ol,
               ushort* __restrict__ Ot,
               int Md, int Nd, int Kd, int lda, int ldb)
{
    __shared__ __align__(16) ushort As[2][128 * 64];
    __shared__ __align__(16) ushort Bs[2][128 * 64];
    const int tid = threadIdx.x;
    const int w = tid >> 6, l = tid & 63;
    const int wr = w >> 1, wc = w & 1;
    const int l15 = l & 15, lg = l >> 4;
    const int row0 = blockIdx.y * 128;
    const int col0 = blockIdx.x * 128;
    const int lrow   = l >> 3;              // 0..7 : row within 8-row stripe
    const int gchunk = (l & 7) ^ lrow;      // pre-swizzled global 16B chunk

    f32x4 acc[4][4];
    #pragma unroll
    for (int m = 0; m < 4; m++)
        #pragma unroll
        for (int n = 0; n < 4; n++)
            acc[m][n] = (f32x4){0.f, 0.f, 0.f, 0.f};

    const int NT = SEGS * (Kd >> 6);
    int sseg = 0, skt = 0;                  // next tile to stage (uniform)

    auto stage = [&](int bi) {
        const ushort* Ap = (sseg == 1) ? A1 : A0;
        const ushort* Bp = (sseg == 2) ? B1 : B0;
        ushort* Asb = &As[bi][0];
        ushort* Bsb = &Bs[bi][0];
        #pragma unroll
        for (int r = 0; r < 4; ++r) {
            int rowb = w * 32 + r * 8;      // wave-uniform stripe base
            int row  = rowb + lrow;
            GL2LDS(Ap + (size_t)(row0 + row) * lda + skt + gchunk * 8,
                   Asb + rowb * 64);
            GL2LDS(Bp + (size_t)(col0 + row) * ldb + skt + gchunk * 8,
                   Bsb + rowb * 64);
        }
        skt += 64;
        if (skt == Kd) { skt = 0; ++sseg; }
    };

    stage(0);
    __syncthreads();                         // drains vmcnt(0): tile0 ready

    for (int t = 0; t < NT; ++t) {
        const int cur = t & 1;
        if (t + 1 < NT) stage(cur ^ 1);      // async prefetch into other buf
        const char* AsB = (const char*)&As[cur][0];
        const char* BsB = (const char*)&Bs[cur][0];
        #pragma unroll
        for (int ks = 0; ks < 2; ++ks) {
            const int g = ks * 4 + lg;
            short8 af[4], bfr[4];
            #pragma unroll
            for (int m = 0; m < 4; ++m) {
                int row = wr * 64 + m * 16 + l15;
                af[m] = *reinterpret_cast<const short8*>(
                    AsB + row * 128 + ((g ^ (row & 7)) << 4));
            }
            #pragma unroll
            for (int n = 0; n < 4; ++n) {
                int row = wc * 64 + n * 16 + l15;
                bfr[n] = *reinterpret_cast<const short8*>(
                    BsB + row * 128 + ((g ^ (row & 7)) << 4));
            }
            #pragma unroll
            for (int m = 0; m < 4; ++m)
                #pragma unroll
                for (int n = 0; n < 4; ++n)
                    acc[m][n] = __builtin_amdgcn_mfma_f32_16x16x32_bf16(
                        af[m], bfr[n], acc[m][n], 0, 0, 0);
        }
        __syncthreads();                     // drains prefetch vmcnt + lgkm
    }

    #pragma unroll
    for (int m = 0; m < 4; ++m) {
        #pragma unroll
        for (int n = 0; n < 4; ++n) {
            int col = col0 + wc * 64 + n * 16 + l15;
            if (TRIPLE) {
                if (col0 < 512) {            // Q part (block-uniform branch)
                    #pragma unroll
                    for (int j = 0; j < 4; ++j) {
                        int row = row0 + wr * 64 + m * 16 + lg * 4 + j;
                        Oh[(size_t)row * 512 + col] = f2bf(acc[m][n][j]);
                    }
                } else if (col0 < 1024) {    // K part
                    #pragma unroll
                    for (int j = 0; j < 4; ++j) {
                        int row = row0 + wr * 64 + m * 16 + lg * 4 + j;
                        Ol[(size_t)row * 512 + (col - 512)] = f2bf(acc[m][n][j]);
                    }
                } else {                     // V part, transposed per batch
                    union { uint2 u; ushort s4[4]; } pk;
                    #pragma unroll
                    for (int j = 0; j < 4; ++j) pk.s4[j] = f2bf(acc[m][n][j]);
                    int brow = row0 + wr * 64 + m * 16 + lg * 4;
                    size_t idx = ((size_t)(brow >> 9) << 18)
                               + (size_t)(col - 1024) * SEQ + (brow & 511);
                    *reinterpret_cast<uint2*>(Ot + idx) = pk.u;
                }
            } else if (TOUT) {
                union { uint2 u; ushort s4[4]; } pk;
                #pragma unroll
                for (int j = 0; j < 4; ++j) pk.s4[j] = f2bf(acc[m][n][j]);
                int brow = row0 + wr * 64 + m * 16 + lg * 4;
                size_t idx = ((size_t)(brow >> 9) << 18) + (size_t)col * SEQ + (brow & 511);
                *reinterpret_cast<uint2*>(Oh + idx) = pk.u;
            } else {
                float bia = 0.f;
                if (BIAS) bia = bias[col];
                #pragma unroll
                for (int j = 0; j < 4; ++j) {
                    int row = row0 + wr * 64 + m * 16 + lg * 4 + j;
                    size_t idx = (size_t)row * Nd + col;
                    float v = acc[m][n][j] + bia;
                    if (RES)  v += bf2f(Rh[idx]) + bf2f(Rl[idx]);
                    if (RELU) v = fmaxf(v, 0.f);
                    ushort hv = f2bf(v);
                    Oh[idx] = hv;
                    if (PAIR) Ol[idx] = f2bf(v - bf2f(hv));
                }
            }
        }
    }
}

// ---------------- MFMA flash attention ------------------------------------
// grid (NHEAD, BATCH, 8): qt-partners (same h,b K/V slice) are 256 apart in
// dispatch order -> same XCD under %8 round-robin -> L2 reuse of K/V.
// 256 threads = 4 waves; wave owns 16 q-rows. Staging via global_load_lds
// (linear LDS dest, pre-swizzled global chunk). O overwrites Q in place.
__global__ __launch_bounds__(256)
void attn_mfma(ushort* __restrict__ QO, const ushort* __restrict__ K,
               const ushort* __restrict__ Vt, const float* __restrict__ maskA)
{
    __shared__ __align__(16) ushort Qs[64 * 64];
    __shared__ __align__(16) ushort Ks[64 * 64];
    __shared__ __align__(16) ushort Vs[64 * 64];
    __shared__ __align__(16) ushort Pl[4][16 * 64];
    __shared__ float ms[64];
    const int h   = blockIdx.x;
    const int b   = blockIdx.y;
    const int qt  = blockIdx.z;
    const int tid = threadIdx.x;
    const int w = tid >> 6, l = tid & 63;
    const int l15 = l & 15, lg = l >> 4, l7 = l & 7;
    const int lrow   = l >> 3;
    const int gchunk = (l & 7) ^ lrow;
    const int qbase = qt * 64;

    // stage Q tile [64 q][64 dh] via global_load_lds, swizzled source
    #pragma unroll
    for (int rr = 0; rr < 2; ++rr) {
        int rowb = rr * 32 + w * 8;             // wave-uniform
        int q = rowb + lrow;
        GL2LDS(QO + ((size_t)(b * SEQ + qbase + q)) * DIM + h * DHEAD + gchunk * 8,
               &Qs[rowb * 64]);
    }
    __syncthreads();

    // hoist Q A-frags (2 k-steps of 32 over DH=64)
    short8 af[2];
    #pragma unroll
    for (int s = 0; s < 2; ++s) {
        int q = w * 16 + l15;
        int c = (s * 4 + lg) ^ l7;
        af[s] = *reinterpret_cast<const short8*>(&Qs[q * 64 + c * 8]);
    }

    f32x4 oacc[4];
    #pragma unroll
    for (int t = 0; t < 4; ++t) oacc[t] = (f32x4){0.f, 0.f, 0.f, 0.f};
    float mrun[4], lrun[4];
    #pragma unroll
    for (int j = 0; j < 4; ++j) { mrun[j] = -INFINITY; lrun[j] = 0.f; }

    ushort* pw = Pl[w];

    for (int kv0 = 0; kv0 < SEQ; kv0 += 64) {
        __syncthreads();
        #pragma unroll
        for (int rr = 0; rr < 2; ++rr) {
            int rowb = rr * 32 + w * 8;
            int row = rowb + lrow;
            GL2LDS(K + ((size_t)(b * SEQ + kv0 + row)) * DIM + h * DHEAD + gchunk * 8,
                   &Ks[rowb * 64]);
            GL2LDS(Vt + ((size_t)b << 18) + (size_t)(h * DHEAD + row) * SEQ + kv0 + gchunk * 8,
                   &Vs[rowb * 64]);
        }
        if (tid < 64) ms[tid] = maskA[b * SEQ + kv0 + tid];
        __syncthreads();

        // QK^T: 4 kv-tiles x 2 k-steps
        f32x4 sacc[4];
        #pragma unroll
        for (int t = 0; t < 4; ++t) sacc[t] = (f32x4){0.f, 0.f, 0.f, 0.f};
        #pragma unroll
        for (int s = 0; s < 2; ++s) {
            int c = (s * 4 + lg) ^ l7;
            #pragma unroll
            for (int t = 0; t < 4; ++t) {
                int kv = t * 16 + l15;
                short8 bf = *reinterpret_cast<const short8*>(&Ks[kv * 64 + c * 8]);
                sacc[t] = __builtin_amdgcn_mfma_f32_16x16x32_bf16(af[s], bf, sacc[t], 0, 0, 0);
            }
        }

        float mk[4];
        #pragma unroll
        for (int t = 0; t < 4; ++t) mk[t] = ms[t * 16 + l15];
        #pragma unroll
        for (int t = 0; t < 4; ++t)
            #pragma unroll
            for (int j = 0; j < 4; ++j)
                sacc[t][j] = (mk[t] != 0.f) ? sacc[t][j] * 0.125f : -1e9f;

        // online softmax, rows q = w*16 + lg*4 + j
        float scl[4];
        #pragma unroll
        for (int j = 0; j < 4; ++j) {
            float tm = fmaxf(fmaxf(sacc[0][j], sacc[1][j]),
                             fmaxf(sacc[2][j], sacc[3][j]));
            tm = fmaxf(tm, __shfl_xor(tm, 1));
            tm = fmaxf(tm, __shfl_xor(tm, 2));
            tm = fmaxf(tm, __shfl_xor(tm, 4));
            tm = fmaxf(tm, __shfl_xor(tm, 8));
            float mn = fmaxf(mrun[j], tm);
            scl[j] = __expf(mrun[j] - mn);
            mrun[j] = mn;
        }
        #pragma unroll
        for (int t = 0; t < 4; ++t)
            #pragma unroll
            for (int j = 0; j < 4; ++j)
                sacc[t][j] = __expf(sacc[t][j] - mrun[j]);
        #pragma unroll
        for (int j = 0; j < 4; ++j) {
            float ps = ((sacc[0][j] + sacc[1][j]) + (sacc[2][j] + sacc[3][j]));
            ps += __shfl_xor(ps, 1);
            ps += __shfl_xor(ps, 2);
            ps += __shfl_xor(ps, 4);
            ps += __shfl_xor(ps, 8);
            lrun[j] = lrun[j] * scl[j] + ps;
        }
        #pragma unroll
        for (int t = 0; t < 4; ++t)
            #pragma unroll
            for (int j = 0; j < 4; ++j)
                oacc[t][j] *= scl[j];

        // P (bf16) -> per-wave LDS [16 q][64 kv], chunk-XOR swizzle on kv
        #pragma unroll
        for (int t = 0; t < 4; ++t) {
            #pragma unroll
            for (int j = 0; j < 4; ++j) {
                int qrow = lg * 4 + j;
                int kv = t * 16 + l15;
                int phys = qrow * 64 + (kv & 7) + ((((kv >> 3) ^ (qrow & 7))) << 3);
                pw[phys] = f2bf(sacc[t][j]);
            }
        }

        // PV: A = P[16 q][64 kv], B = Vt[dh][kv]; 2 k-steps x 4 dh-tiles
        #pragma unroll
        for (int s = 0; s < 2; ++s) {
            int c = (s * 4 + lg) ^ l7;
            short8 pa = *reinterpret_cast<const short8*>(&pw[l15 * 64 + c * 8]);
            #pragma unroll
            for (int t = 0; t < 4; ++t) {
                int dh = t * 16 + l15;
                short8 vb = *reinterpret_cast<const short8*>(&Vs[dh * 64 + c * 8]);
                oacc[t] = __builtin_amdgcn_mfma_f32_16x16x32_bf16(pa, vb, oacc[t], 0, 0, 0);
            }
        }
    }

    // epilogue: O[q][h*64+dh] = oacc / lrun, in place over Q
    float inv[4];
    #pragma unroll
    for (int j = 0; j < 4; ++j) inv[j] = 1.0f / lrun[j];
    #pragma unroll
    for (int t = 0; t < 4; ++t) {
        #pragma unroll
        for (int j = 0; j < 4; ++j) {
            size_t g = ((size_t)(b * SEQ + qbase + w * 16 + lg * 4 + j)) * DIM
                     + h * DHEAD + t * 16 + l15;
            QO[g] = f2bf(oacc[t][j] * inv[j]);
        }
    }
}

// ---------------- masked mean pool (reads bf16 hi/lo h) --------------------
// grid (BATCH, 4): block handles 128 d-cols; 8-way s-split, uint vec loads.
__global__ __launch_bounds__(512)
void pool_kernel(const ushort* __restrict__ hh, const ushort* __restrict__ hl,
                 const float* __restrict__ maskA, float* __restrict__ pooled)
{
    int b  = blockIdx.x;
    int dq = blockIdx.y;
    int dl = threadIdx.x & 63;       // 64 d-pairs
    int sg = threadIdx.x >> 6;       // 0..7 s-group
    int d  = dq * 128 + dl * 2;
    float a0 = 0.f, a1 = 0.f, cnt = 0.f;
    for (int s = sg; s < SEQ; s += 8) {
        float mv = maskA[b * SEQ + s];
        size_t idx = ((size_t)(b * SEQ + s)) * DIM + d;
        unsigned vh = *reinterpret_cast<const unsigned*>(&hh[idx]);
        unsigned vl = *reinterpret_cast<const unsigned*>(&hl[idx]);
        a0 += mv * (bf2f((ushort)(vh & 0xffff)) + bf2f((ushort)(vl & 0xffff)));
        a1 += mv * (bf2f((ushort)(vh >> 16))    + bf2f((ushort)(vl >> 16)));
        cnt += mv;
    }
    __shared__ float r0[8][64];
    __shared__ float r1[8][64];
    __shared__ float rc[8];
    r0[sg][dl] = a0;
    r1[sg][dl] = a1;
    if (dl == 0) rc[sg] = cnt;
    __syncthreads();
    if (sg == 0) {
        float t0 = 0.f, t1 = 0.f, c = 0.f;
        #pragma unroll
        for (int g = 0; g < 8; ++g) { t0 += r0[g][dl]; t1 += r1[g][dl]; c += rc[g]; }
        float invc = 1.0f / fmaxf(c, 1.f);
        pooled[b * DIM + d]     = t0 * invc;
        pooled[b * DIM + d + 1] = t1 * invc;
    }
}

// ---------------- pooled @ Wp + bp -> henc rows [hoff, hoff+32) ------------
__global__ __launch_bounds__(512)
void proj_kernel(const float* __restrict__ pooled, const float* __restrict__ Wp,
                 const float* __restrict__ bp, float* __restrict__ henc, int hoff)
{
    int b = blockIdx.x;
    int j = threadIdx.x;
    __shared__ float p[DIM];
    p[j] = pooled[b * DIM + j];
    __syncthreads();
    float a0 = 0.f, a1 = 0.f, a2 = 0.f, a3 = 0.f;
    for (int d = 0; d < DIM; d += 4) {
        a0 += p[d]     * Wp[(size_t)d       * DIM + j];
        a1 += p[d + 1] * Wp[(size_t)(d + 1) * DIM + j];
        a2 += p[d + 2] * Wp[(size_t)(d + 2) * DIM + j];
        a3 += p[d + 3] * Wp[(size_t)(d + 3) * DIM + j];
    }
    henc[(size_t)(hoff + b) * DIM + j] = ((a0 + a1) + (a2 + a3)) + bp[j];
}

// ---------------- logits = concat(hH,hF) @ W_out + b_out -------------------
__global__ __launch_bounds__(256)
void logits_kernel(const float* __restrict__ henc, const float* __restrict__ Wout,
                   const float* __restrict__ bout, float* __restrict__ logits)
{
    int b = blockIdx.y;
    int m = blockIdx.x * 256 + threadIdx.x;
    __shared__ float hh[2 * DIM];
    for (int j = threadIdx.x; j < DIM; j += 256) {
        hh[j]       = henc[(size_t)b * DIM + j];
        hh[DIM + j] = henc[(size_t)(BATCH + b) * DIM + j];
    }
    __syncthreads();
    if (m < MM) {
        float a0 = 0.f, a1 = 0.f, a2 = 0.f, a3 = 0.f;
        for (int j = 0; j < 2 * DIM; j += 4) {
            a0 += hh[j]     * Wout[(size_t)j       * MM + m];
            a1 += hh[j + 1] * Wout[(size_t)(j + 1) * MM + m];
            a2 += hh[j + 2] * Wout[(size_t)(j + 2) * MM + m];
            a3 += hh[j + 3] * Wout[(size_t)(j + 3) * MM + m];
        }
        logits[b * MM + m] = ((a0 + a1) + (a2 + a3)) + bout[m];
    }
}

// ---------------- softmax + argmax ----------------
__global__ __launch_bounds__(256)
void smax_kernel(const float* __restrict__ logits, float* __restrict__ out)
{
    int b   = blockIdx.x;
    int tid = threadIdx.x;
    __shared__ float red[256];
    __shared__ int   redi[256];

    float v[4];
    float mx = -INFINITY;
    #pragma unroll
    for (int i = 0; i < 4; i++) {
        int m = tid + i * 256;
        if (m < MM) { v[i] = logits[b * MM + m]; mx = fmaxf(mx, v[i]); }
        else v[i] = -INFINITY;
    }
    red[tid] = mx; __syncthreads();
    for (int st = 128; st > 0; st >>= 1) {
        if (tid < st) red[tid] = fmaxf(red[tid], red[tid + st]);
        __syncthreads();
    }
    mx = red[0]; __syncthreads();

    float sum = 0.f;
    #pragma unroll
    for (int i = 0; i < 4; i++) {
        int m = tid + i * 256;
        if (m < MM) { v[i] = expf(v[i] - mx); sum += v[i]; }
    }
    red[tid] = sum; __syncthreads();
    for (int st = 128; st > 0; st >>= 1) {
        if (tid < st) red[tid] += red[tid + st];
        __syncthreads();
    }
    float inv = 1.0f / red[0]; __syncthreads();

    float bestv = -INFINITY; int besti = 0x7fffffff;
    #pragma unroll
    for (int i = 0; i < 4; i++) {
        int m = tid + i * 256;
        if (m < MM) {
            float lam = v[i] * inv;
            out[b * MM + m] = lam;
            if (lam > bestv) { bestv = lam; besti = m; }
        }
    }
    red[tid] = bestv; redi[tid] = besti; __syncthreads();
    for (int st = 128; st > 0; st >>= 1) {
        if (tid < st) {
            float ov = red[tid + st]; int oi = redi[tid + st];
            if (ov > red[tid] || (ov == red[tid] && oi < redi[tid])) {
                red[tid] = ov; redi[tid] = oi;
            }
        }
        __syncthreads();
    }
    if (tid == 0) out[BATCH * MM + b] = (float)redi[0];
}

// ---------------------------------------------------------------------------
extern "C" void kernel_launch(void* const* d_in, const int* in_sizes, int n_in,
                              void* d_out, int out_size, void* d_ws, size_t ws_size,
                              hipStream_t stream)
{
    const float* xH   = (const float*)d_in[0];
    const float* xF   = (const float*)d_in[1];
    const float* Wm   = (const float*)d_in[2];
    const float* Wt   = (const float*)d_in[3];
    const float* bt   = (const float*)d_in[4];
    const float* Wq   = (const float*)d_in[5];
    const float* Wk   = (const float*)d_in[6];
    const float* Wv   = (const float*)d_in[7];
    const float* Wo   = (const float*)d_in[8];
    const float* W1   = (const float*)d_in[9];
    const float* b1   = (const float*)d_in[10];
    const float* W2   = (const float*)d_in[11];
    const float* b2   = (const float*)d_in[12];
    const float* Wp   = (const float*)d_in[13];
    const float* bp   = (const float*)d_in[14];
    const float* Wout = (const float*)d_in[15];
    const float* bout = (const float*)d_in[16];
    float* out = (float*)d_out;

    float* ws     = (float*)d_ws;
    float*  WmT    = ws + OFF_WMT;
    float*  maskA  = ws + OFF_MASK;
    float*  pooled = ws + OFF_POOL;
    float*  henc   = ws + OFF_HENC;
    float*  logits = ws + OFF_LOG;
    ushort* WqkvTh = (ushort*)(ws + OFF_WQTH);  // [1536][512] concat Wq|Wk|Wv
    ushort* WkTh   = (ushort*)(ws + OFF_WKTH);
    ushort* WvTh   = (ushort*)(ws + OFF_WVTH);
    ushort* WoTh   = (ushort*)(ws + OFF_WOTH);
    ushort* W1Th   = (ushort*)(ws + OFF_W1TH);
    ushort* W1Tl   = (ushort*)(ws + OFF_W1TL);
    ushort* W2Th   = (ushort*)(ws + OFF_W2TH);
    ushort* W2Tl   = (ushort*)(ws + OFF_W2TL);
    ushort* ehi    = (ushort*)(ws + OFF_EHI);
    ushort* elo    = (ushort*)(ws + OFF_ELO);
    ushort* Qb     = (ushort*)(ws + OFF_QB);   // Q -> O -> h'_hi
    ushort* Kb     = (ushort*)(ws + OFF_KB);   // K -> h'_lo
    ushort* Vtb    = (ushort*)(ws + OFF_VB);   // V^T per batch
    ushort* rhi    = (ushort*)(ws + OFF_RHI);
    ushort* rlo    = (ushort*)(ws + OFF_RLO);

    // ---- setup (shared by both passes) ----
    transpose_wm<<<dim3(32, 16), 256, 0, stream>>>(Wm, WmT);
    split_wT<false><<<dim3(16, 16), 256, 0, stream>>>(Wq, WqkvTh, nullptr, DIM, DIM);
    split_wT<false><<<dim3(16, 16), 256, 0, stream>>>(Wk, WkTh, nullptr, DIM, DIM);
    split_wT<false><<<dim3(16, 16), 256, 0, stream>>>(Wv, WvTh, nullptr, DIM, DIM);
    split_wT<false><<<dim3(16, 16), 256, 0, stream>>>(Wo, WoTh, nullptr, DIM, DIM);
    split_wT<true ><<<dim3(64, 16), 256, 0, stream>>>(W1, W1Th, W1Tl, DIM, DFFN);
    split_wT<true ><<<dim3(16, 64), 256, 0, stream>>>(W2, W2Th, W2Tl, DFFN, DIM);

    for (int p = 0; p < 2; p++) {
        const float* x = (p == 0) ? xH : xF;
        // embedding -> e hi/lo + mask
        embed_kernel<<<dim3(ROWS), 256, 0, stream>>>(x, WmT, Wt, bt, ehi, elo, maskA);
        // fused QKV: [16384,512] @ [512,1536]^T; Q->Qb, K->Kb, V->Vtb (trans)
        gemm_bf16<1,false,false,false,false,false,true><<<dim3(12, 128), 256, 0, stream>>>(
            ehi, nullptr, WqkvTh, nullptr, nullptr, nullptr, nullptr,
            Qb, Kb, Vtb, ROWS, 512, DIM, DIM, DIM);
        // MFMA attention, O overwrites Q
        attn_mfma<<<dim3(NHEAD, BATCH, 8), 256, 0, stream>>>(Qb, Kb, Vtb, maskA);
        // h = e + O @ Wo   (res from e hi/lo, out hi/lo in place over e)
        gemm_bf16<1,false,false,true,true,false,false><<<dim3(4, 128), 256, 0, stream>>>(
            Qb, nullptr, WoTh, nullptr, nullptr, ehi, elo,
            ehi, elo, nullptr, ROWS, DIM, DIM, DIM, DIM);
        // FFN over 4 DFF-chunks of 512; split-3 both GEMMs; accumulate into h'
        for (int nc = 0; nc < 4; nc++) {
            gemm_bf16<3,true,true,false,true,false,false><<<dim3(4, 128), 256, 0, stream>>>(
                ehi, elo, W1Th + (size_t)nc * 512 * DIM, W1Tl + (size_t)nc * 512 * DIM,
                b1 + nc * 512, nullptr, nullptr,
                rhi, rlo, nullptr, ROWS, 512, DIM, DIM, DIM);
            if (nc == 0)
                gemm_bf16<3,true,false,true,true,false,false><<<dim3(4, 128), 256, 0, stream>>>(
                    rhi, rlo, W2Th + nc * 512, W2Tl + nc * 512,
                    b2, ehi, elo,
                    Qb, Kb, nullptr, ROWS, DIM, 512, 512, DFFN);
            else
                gemm_bf16<3,false,false,true,true,false,false><<<dim3(4, 128), 256, 0, stream>>>(
                    rhi, rlo, W2Th + nc * 512, W2Tl + nc * 512,
                    nullptr, Qb, Kb,
                    Qb, Kb, nullptr, ROWS, DIM, 512, 512, DFFN);
        }
        // masked mean pool over h' (hi in Qb, lo in Kb)
        pool_kernel<<<dim3(BATCH, 4), 512, 0, stream>>>(Qb, Kb, maskA, pooled);
        // pooled @ Wp + bp
        proj_kernel<<<dim3(BATCH), 512, 0, stream>>>(pooled, Wp, bp, henc, p * BATCH);
    }

    // head
    logits_kernel<<<dim3(4, BATCH), 256, 0, stream>>>(henc, Wout, bout, logits);
    smax_kernel<<<dim3(BATCH), 256, 0, stream>>>(logits, out);
}